// Round 17
// baseline (107.729 us; speedup 1.0000x reference)
//
#include <hip/hip_runtime.h>
#include <hip/hip_bf16.h>

// Head: k/q/v projection + causal softmax attention, single head.
// B=8, T=4096, C=1024, H=64. All inputs fp32; output fp32.
//   k0: wT2 = [Wq|Wk|Wv]^T per-chunk staged layout (q cols pre-scaled).
//   k1: qkv v8: DOUBLE-buffered gl_lds pipeline (40KB LDS -> 4 blocks/CU =
//       4 waves/SIMD), vmcnt(5), 32 phases of K=32. R16 falsified depth>2
//       (quad buffer -2.6us); both kernels were latency-bound at 2 waves/SIMD
//       -> trade pipeline depth for TLP.
//   k2: flash attention: 32x32x16 swapped-operand, lane-local softmax,
//       shfl_xor(32), paired (ti,127-ti) tiles, 4-way KV split. Merge now
//       SEQUENTIAL through one 36KB scratch (was 72KB) -> 3 blocks/CU.

#define HS 64
#define NE 1024
#define NB 8
#define TS 4096
#define NROW (NB * TS)  // 32768

#define QKV_BUF 20480   // per buffer: 12288 W + 8192 X
#define QKV_XB  12288

typedef __attribute__((ext_vector_type(4)))  float f32x4;
typedef __attribute__((ext_vector_type(16))) float f32x16;
typedef __attribute__((ext_vector_type(8)))  short s16x8;   // bf16x8 MFMA fragment
typedef __attribute__((ext_vector_type(4)))  float vfloat4;

__device__ __forceinline__ unsigned short f2bf(float x) {
  return __builtin_bit_cast(unsigned short, __float2bfloat16(x));
}
__device__ __forceinline__ unsigned pkbf(float lo, float hi) {
  return (unsigned)f2bf(lo) | ((unsigned)f2bf(hi) << 16);
}

union ABFrag { s16x8 v; unsigned d[4]; };

__device__ __forceinline__ void gl_lds16(const void* g, const unsigned char* l) {
  __builtin_amdgcn_global_load_lds(
      (const __attribute__((address_space(1))) unsigned int*)(g),
      (__attribute__((address_space(3))) unsigned int*)(l), 16, 0, 0);
}

// ---------------- kernel 0: weight transpose+cast, per-chunk layout ----
__global__ __launch_bounds__(256) void wt_kernel(const float* __restrict__ Wk,
                                                 const float* __restrict__ Wq,
                                                 const float* __restrict__ Wv,
                                                 unsigned short* __restrict__ wT2) {
  int gid = blockIdx.x * 256 + threadIdx.x;   // 0..196607
  int j = gid & 7;
  int t1 = gid >> 3;          // 0..24575
  int sk = t1 % 768;
  int c  = t1 / 768;          // 0..31
  int g = sk / 192, n = sk % 192;
  int k = c * 32 + g * 8 + j;
  const float* W = (n < 64) ? Wq : (n < 128) ? Wk : Wv;
  float s = (n < 64) ? 0.18033688011112042f : 1.0f;  // 0.125 * log2(e)
  wT2[gid] = f2bf(W[k * 64 + (n & 63)] * s);
}

// ---------------- kernel 1: fused QKV projection v8 ----------------
// Block 256 thd = 4 waves, 64 rows (16/wave), all 192 cols. 32 phases, K=32.
// Double buffer (c&1), issue c+2 after compute, vmcnt(5); tail 5/0.
// 40KB LDS + VGPR<=128 -> 4 blocks/CU = 4 waves/SIMD (TLP latency hiding).
__global__ __launch_bounds__(256, 4) void qkv_kernel(const float* __restrict__ x,
                                                     const unsigned short* __restrict__ wT2,
                                                     unsigned short* __restrict__ q_ws,
                                                     unsigned short* __restrict__ k_ws,
                                                     unsigned short* __restrict__ vT) {
  __shared__ __align__(16) unsigned char smem[2 * QKV_BUF];  // 40960 B
  const int t = threadIdx.x;
  const int w = t >> 6, lane = t & 63;
  const int g = lane >> 4, nn = lane & 15;
  const int m0blk = blockIdx.x * 64;
  const int m0 = m0blk + w * 16;

  f32x4 acc[12];
#pragma unroll
  for (int i = 0; i < 12; ++i) acc[i] = f32x4{0.f, 0.f, 0.f, 0.f};

  // ---- staging sources ----
  const unsigned short* wsrcA = wT2 + (size_t)(w * 192 + lane) * 8;  // +c*6144
  const int wd0 = w * 3072;                                          // +p*1024
  const float* xs0 = x + (size_t)(m0blk + w * 16 + 0 + (lane >> 3)) * NE + (lane & 7) * 4;
  const float* xs1 = x + (size_t)(m0blk + w * 16 + 8 + (lane >> 3)) * NE + (lane & 7) * 4;
  const int xd0 = QKV_XB + w * 2048;
  const int xd1 = xd0 + 1024;

  // ---- read offsets ----
  const int abase = QKV_XB + (w * 16 + nn) * 128 + g * 32;
  const int wbase = (g * 192 + nn) * 16;

#define ISSUE(C)                                                               \
  {                                                                            \
    unsigned char* db_ = smem + ((C) & 1) * QKV_BUF;                           \
    gl_lds16(wsrcA + (size_t)(C) * 6144, db_ + wd0);                           \
    gl_lds16(wsrcA + (size_t)(C) * 6144 + 512, db_ + wd0 + 1024);              \
    gl_lds16(wsrcA + (size_t)(C) * 6144 + 1024, db_ + wd0 + 2048);             \
    gl_lds16(xs0 + (C) * 32, db_ + xd0);                                       \
    gl_lds16(xs1 + (C) * 32, db_ + xd1);                                       \
  }

  // ---- prologue: clusters 0,1 in order ----
  ISSUE(0)
  __builtin_amdgcn_sched_barrier(0);
  ISSUE(1)
  __builtin_amdgcn_sched_barrier(0);

#define PHASE(C, VM, DOISS)                                                    \
  {                                                                            \
    asm volatile("s_waitcnt vmcnt(" #VM ")" ::: "memory");                     \
    __builtin_amdgcn_s_barrier();                                              \
    __builtin_amdgcn_sched_barrier(0);                                         \
    const unsigned char* bb_ = smem + ((C) & 1) * QKV_BUF;                     \
    const vfloat4 a0_ = *(const vfloat4*)(bb_ + abase);                        \
    const vfloat4 a1_ = *(const vfloat4*)(bb_ + abase + 16);                   \
    ABFrag af;                                                                 \
    af.d[0] = pkbf(a0_.x, a0_.y); af.d[1] = pkbf(a0_.z, a0_.w);                \
    af.d[2] = pkbf(a1_.x, a1_.y); af.d[3] = pkbf(a1_.z, a1_.w);                \
    _Pragma("unroll")                                                          \
    for (int i = 0; i < 12; ++i) {                                             \
      const s16x8 bf = *(const s16x8*)(bb_ + wbase + i * 256);                 \
      acc[i] = __builtin_amdgcn_mfma_f32_16x16x32_bf16(af.v, bf, acc[i], 0, 0, 0); \
    }                                                                          \
    __builtin_amdgcn_sched_barrier(0);                                         \
    __builtin_amdgcn_s_barrier();                                              \
    __builtin_amdgcn_sched_barrier(0);                                         \
    if (DOISS) { ISSUE((C) + 2) }                                              \
    __builtin_amdgcn_sched_barrier(0);                                         \
  }

#pragma unroll
  for (int c = 0; c < 30; ++c) PHASE(c, 5, 1)
  PHASE(30, 5, 0)
  PHASE(31, 0, 0)
#undef PHASE
#undef ISSUE

  // ---- epilogue: D row = m0 + 4g + j, col = 16i + nn ----
  const int rbase = m0 + 4 * g;
#pragma unroll
  for (int i = 0; i < 12; ++i) {
    const int c = 16 * i + nn;
#pragma unroll
    for (int j = 0; j < 4; ++j) {
      const int rr = rbase + j;
      const unsigned short h = f2bf(acc[i][j]);
      if (c < 64) {
        q_ws[(size_t)rr * HS + c] = h;
      } else if (c < 128) {
        k_ws[(size_t)rr * HS + (c - 64)] = h;
      } else {
        const int b = rr >> 12, tt = rr & 4095;
        vT[((size_t)(b * HS + (c - 128))) * TS + tt] = h;
      }
    }
  }
}

// ---------------- kernel 2: causal flash attention, 32x32 lane-local -------
// S^T(32kv x 32q) = sum_kk mfma32x32x16(K-frag, Q^T-frag). Lane (qi,hi) holds
// st_[r] = S^T[kv=(r&3)+8*(r>>2)+4hi][q=qi]; the other 16 kv live in lane^32.
// Reduces and P^T B-frag assembly use __shfl_xor(...,32).
#define TILE32(S0, DIAG, QF, M_RUN, L_RUN, O)                                  \
  {                                                                            \
    const int s0_ = (S0);                                                      \
    const unsigned short* kr_ = kptr + (size_t)(s0_ + qi) * HS + hi8;          \
    const s16x8 ka0_ = *(const s16x8*)(kr_);                                   \
    const s16x8 ka1_ = *(const s16x8*)(kr_ + 16);                              \
    const s16x8 ka2_ = *(const s16x8*)(kr_ + 32);                              \
    const s16x8 ka3_ = *(const s16x8*)(kr_ + 48);                              \
    const unsigned short* vr0_ = vptr + (size_t)qi * TS + s0_ + hi8;           \
    const unsigned short* vr1_ = vptr + (size_t)(32 + qi) * TS + s0_ + hi8;    \
    f32x16 st_;                                                                \
    _Pragma("unroll") for (int r = 0; r < 16; ++r) st_[r] = 0.f;               \
    st_ = __builtin_amdgcn_mfma_f32_32x32x16_bf16(ka0_, QF[0], st_, 0, 0, 0);  \
    st_ = __builtin_amdgcn_mfma_f32_32x32x16_bf16(ka1_, QF[1], st_, 0, 0, 0);  \
    st_ = __builtin_amdgcn_mfma_f32_32x32x16_bf16(ka2_, QF[2], st_, 0, 0, 0);  \
    st_ = __builtin_amdgcn_mfma_f32_32x32x16_bf16(ka3_, QF[3], st_, 0, 0, 0);  \
    if (DIAG) {                                                                \
      _Pragma("unroll") for (int r = 0; r < 16; ++r) {                         \
        const int kvl_ = (r & 3) + 8 * (r >> 2) + hi4;                         \
        if (kvl_ > qi) st_[r] = -1e30f;                                        \
      }                                                                        \
    }                                                                          \
    float mx_ =                                                                \
      fmaxf(fmaxf(fmaxf(fmaxf(st_[0], st_[1]), fmaxf(st_[2], st_[3])),         \
                  fmaxf(fmaxf(st_[4], st_[5]), fmaxf(st_[6], st_[7]))),        \
            fmaxf(fmaxf(fmaxf(st_[8], st_[9]), fmaxf(st_[10], st_[11])),       \
                  fmaxf(fmaxf(st_[12], st_[13]), fmaxf(st_[14], st_[15]))));   \
    mx_ = fmaxf(mx_, __shfl_xor(mx_, 32, 64));                                 \
    const float mn_ = fmaxf(M_RUN, mx_);                                       \
    if (__ballot(mn_ > M_RUN)) {                                               \
      const float fs_ = __builtin_amdgcn_exp2f(M_RUN - mn_);                   \
      _Pragma("unroll") for (int r = 0; r < 16; ++r) {                         \
        O[0][r] *= fs_; O[1][r] *= fs_;                                        \
      }                                                                        \
      L_RUN *= fs_;                                                            \
      M_RUN = mn_;                                                             \
    }                                                                          \
    float p_[16];                                                              \
    _Pragma("unroll") for (int r = 0; r < 16; ++r)                             \
      p_[r] = __builtin_amdgcn_exp2f(st_[r] - M_RUN);                          \
    float sm_ = ((p_[0] + p_[1]) + (p_[2] + p_[3])) +                          \
                ((p_[4] + p_[5]) + (p_[6] + p_[7]));                           \
    sm_ += ((p_[8] + p_[9]) + (p_[10] + p_[11])) +                             \
           ((p_[12] + p_[13]) + (p_[14] + p_[15]));                            \
    sm_ += __shfl_xor(sm_, 32, 64);                                            \
    L_RUN += sm_;                                                              \
    const unsigned q01_ = pkbf(p_[0], p_[1]),   q23_ = pkbf(p_[2], p_[3]);     \
    const unsigned q45_ = pkbf(p_[4], p_[5]),   q67_ = pkbf(p_[6], p_[7]);     \
    const unsigned q89_ = pkbf(p_[8], p_[9]),   qab_ = pkbf(p_[10], p_[11]);   \
    const unsigned qcd_ = pkbf(p_[12], p_[13]), qef_ = pkbf(p_[14], p_[15]);   \
    const unsigned t01_ = (unsigned)__shfl_xor((int)q01_, 32, 64);             \
    const unsigned t23_ = (unsigned)__shfl_xor((int)q23_, 32, 64);             \
    const unsigned t45_ = (unsigned)__shfl_xor((int)q45_, 32, 64);             \
    const unsigned t67_ = (unsigned)__shfl_xor((int)q67_, 32, 64);             \
    const unsigned t89_ = (unsigned)__shfl_xor((int)q89_, 32, 64);             \
    const unsigned tab_ = (unsigned)__shfl_xor((int)qab_, 32, 64);             \
    const unsigned tcd_ = (unsigned)__shfl_xor((int)qcd_, 32, 64);             \
    const unsigned tef_ = (unsigned)__shfl_xor((int)qef_, 32, 64);             \
    ABFrag pf0_, pf1_;                                                         \
    pf0_.d[0] = hi ? t45_ : q01_;                                              \
    pf0_.d[1] = hi ? t67_ : q23_;                                              \
    pf0_.d[2] = hi ? q45_ : t01_;                                              \
    pf0_.d[3] = hi ? q67_ : t23_;                                              \
    pf1_.d[0] = hi ? tcd_ : q89_;                                              \
    pf1_.d[1] = hi ? tef_ : qab_;                                              \
    pf1_.d[2] = hi ? qcd_ : t89_;                                              \
    pf1_.d[3] = hi ? qef_ : tab_;                                              \
    const s16x8 vf00_ = *(const s16x8*)(vr0_);                                 \
    const s16x8 vf01_ = *(const s16x8*)(vr0_ + 16);                            \
    const s16x8 vf10_ = *(const s16x8*)(vr1_);                                 \
    const s16x8 vf11_ = *(const s16x8*)(vr1_ + 16);                            \
    O[0] = __builtin_amdgcn_mfma_f32_32x32x16_bf16(vf00_, pf0_.v, O[0], 0,0,0);\
    O[0] = __builtin_amdgcn_mfma_f32_32x32x16_bf16(vf01_, pf1_.v, O[0], 0,0,0);\
    O[1] = __builtin_amdgcn_mfma_f32_32x32x16_bf16(vf10_, pf0_.v, O[1], 0,0,0);\
    O[1] = __builtin_amdgcn_mfma_f32_32x32x16_bf16(vf11_, pf1_.v, O[1], 0,0,0);\
  }

__global__ __launch_bounds__(256, 3) void attn_kernel(const unsigned short* __restrict__ q_ws,
                                                      const unsigned short* __restrict__ k_ws,
                                                      const unsigned short* __restrict__ vT,
                                                      float* __restrict__ out) {
  __shared__ float o_sm[4][32][68];    // shared scratch, reused for A then B
  __shared__ float lm_sm[4][32][2];

  const int wv = threadIdx.x >> 6, lane = threadIdx.x & 63;
  const int qi = lane & 31, hi = lane >> 5;
  const int hi8 = 8 * hi, hi4 = 4 * hi;

  const int bid = blockIdx.x;             // 0..511
  const int b = bid & 7;                  // batch <-> XCD alignment
  const int pr = bid >> 3;                // 0..63
  const int tiA = pr, tiB = 127 - pr;     // paired long/short 32-row tiles
  const int t0A = tiA * 32, t0B = tiB * 32;

  const unsigned short* kptr = k_ws + (size_t)b * TS * HS;
  const unsigned short* vptr = vT + (size_t)b * HS * TS;
  const unsigned short* qrA = q_ws + (size_t)(b * TS + t0A + qi) * HS + hi8;
  const unsigned short* qrB = q_ws + (size_t)(b * TS + t0B + qi) * HS + hi8;

  s16x8 qfA[4], qfB[4];
#pragma unroll
  for (int kk = 0; kk < 4; ++kk) {
    qfA[kk] = *(const s16x8*)(qrA + 16 * kk);
    qfB[kk] = *(const s16x8*)(qrB + 16 * kk);
  }

  f32x16 oA[2], oB[2];
#pragma unroll
  for (int r = 0; r < 16; ++r) { oA[0][r] = 0.f; oA[1][r] = 0.f; oB[0][r] = 0.f; oB[1][r] = 0.f; }
  float mA = -1e30f, lA = 0.f, mB = -1e30f, lB = 0.f;

  const int ntA = tiA + 1, ntB = tiB + 1;
  for (int it = wv; it < ntB; it += 4) {
    const int s0 = it * 32;
    if (it < ntA) TILE32(s0, it == tiA, qfA, mA, lA, oA)
    TILE32(s0, it == tiB, qfB, mB, lB, oB)
  }

  const int q = threadIdx.x >> 3;         // 0..31
  const int h0 = (threadIdx.x & 7) * 8;   // 0..56

  // ---- tile A: partials -> LDS, merge, store ----
#pragma unroll
  for (int ht = 0; ht < 2; ++ht)
#pragma unroll
    for (int r = 0; r < 16; ++r)
      o_sm[wv][qi][ht * 32 + (r & 3) + 8 * (r >> 2) + hi4] = oA[ht][r];
  if (lane < 32) { lm_sm[wv][lane][0] = mA; lm_sm[wv][lane][1] = lA; }
  __syncthreads();
  {
    const float m0v = lm_sm[0][q][0], m1v = lm_sm[1][q][0];
    const float m2v = lm_sm[2][q][0], m3v = lm_sm[3][q][0];
    const float M = fmaxf(fmaxf(m0v, m1v), fmaxf(m2v, m3v));
    const float w0 = __builtin_amdgcn_exp2f(m0v - M);
    const float w1 = __builtin_amdgcn_exp2f(m1v - M);
    const float w2 = __builtin_amdgcn_exp2f(m2v - M);
    const float w3 = __builtin_amdgcn_exp2f(m3v - M);
    const float L = w0 * lm_sm[0][q][1] + w1 * lm_sm[1][q][1] +
                    w2 * lm_sm[2][q][1] + w3 * lm_sm[3][q][1];
    const float inv = 1.0f / L;
    float rv[8];
#pragma unroll
    for (int j = 0; j < 8; ++j)
      rv[j] = (w0 * o_sm[0][q][h0 + j] + w1 * o_sm[1][q][h0 + j] +
               w2 * o_sm[2][q][h0 + j] + w3 * o_sm[3][q][h0 + j]) * inv;
    float* ob = out + ((size_t)(b * TS + t0A + q)) * HS + h0;
    *(float4*)(ob)     = float4{rv[0], rv[1], rv[2], rv[3]};
    *(float4*)(ob + 4) = float4{rv[4], rv[5], rv[6], rv[7]};
  }
  __syncthreads();

  // ---- tile B: partials -> LDS (reuse), merge, store ----
#pragma unroll
  for (int ht = 0; ht < 2; ++ht)
#pragma unroll
    for (int r = 0; r < 16; ++r)
      o_sm[wv][qi][ht * 32 + (r & 3) + 8 * (r >> 2) + hi4] = oB[ht][r];
  if (lane < 32) { lm_sm[wv][lane][0] = mB; lm_sm[wv][lane][1] = lB; }
  __syncthreads();
  {
    const float m0v = lm_sm[0][q][0], m1v = lm_sm[1][q][0];
    const float m2v = lm_sm[2][q][0], m3v = lm_sm[3][q][0];
    const float M = fmaxf(fmaxf(m0v, m1v), fmaxf(m2v, m3v));
    const float w0 = __builtin_amdgcn_exp2f(m0v - M);
    const float w1 = __builtin_amdgcn_exp2f(m1v - M);
    const float w2 = __builtin_amdgcn_exp2f(m2v - M);
    const float w3 = __builtin_amdgcn_exp2f(m3v - M);
    const float L = w0 * lm_sm[0][q][1] + w1 * lm_sm[1][q][1] +
                    w2 * lm_sm[2][q][1] + w3 * lm_sm[3][q][1];
    const float inv = 1.0f / L;
    float rv[8];
#pragma unroll
    for (int j = 0; j < 8; ++j)
      rv[j] = (w0 * o_sm[0][q][h0 + j] + w1 * o_sm[1][q][h0 + j] +
               w2 * o_sm[2][q][h0 + j] + w3 * o_sm[3][q][h0 + j]) * inv;
    float* ob = out + ((size_t)(b * TS + t0B + q)) * HS + h0;
    *(float4*)(ob)     = float4{rv[0], rv[1], rv[2], rv[3]};
    *(float4*)(ob + 4) = float4{rv[4], rv[5], rv[6], rv[7]};
  }
}

extern "C" void kernel_launch(void* const* d_in, const int* in_sizes, int n_in,
                              void* d_out, int out_size, void* d_ws, size_t ws_size,
                              hipStream_t stream) {
  const float* x  = (const float*)d_in[0];
  const float* Wk = (const float*)d_in[1];
  const float* Wq = (const float*)d_in[2];
  const float* Wv = (const float*)d_in[3];
  float* out = (float*)d_out;

  unsigned short* wT2  = (unsigned short*)d_ws;
  unsigned short* q_ws = wT2 + 192 * 1024;
  unsigned short* k_ws = q_ws + (size_t)NROW * HS;
  unsigned short* vT   = k_ws + (size_t)NROW * HS;

  wt_kernel<<<dim3(768), dim3(256), 0, stream>>>(Wk, Wq, Wv, wT2);
  qkv_kernel<<<dim3(NROW / 64), dim3(256), 0, stream>>>(x, wT2, q_ws, k_ws, vT);
  attn_kernel<<<dim3(512), dim3(256), 0, stream>>>(q_ws, k_ws, vT, out);
}

// Round 18
// 99.369 us; speedup vs baseline: 1.0841x; 1.0841x over previous
//
#include <hip/hip_runtime.h>
#include <hip/hip_bf16.h>

// Head: k/q/v projection + causal softmax attention, single head.
// B=8, T=4096, C=1024, H=64. All inputs fp32; output fp32.
//   k0: wT2 = [Wq|Wk|Wv]^T per-chunk staged layout (q cols pre-scaled).
//   k1: qkv v8 (R17-verified ~20us): double-buffered gl_lds pipeline,
//       vmcnt(5), 32 phases of K=32, 40KB LDS -> 4 blocks/CU.
//   k2: flash attention: 32x32x16 swapped-operand, lane-local softmax,
//       shfl_xor(32), paired (ti,127-ti) tiles, 4-way KV split, sequential
//       36KB merge. launch_bounds (256,2): R17's (256,3) forced VGPR=84 <
//       ~96 live -> scratch spill in loop (49->85us). Cap 256 -> ~150 VGPR,
//       no spill, natural 3 waves/SIMD.

#define HS 64
#define NE 1024
#define NB 8
#define TS 4096
#define NROW (NB * TS)  // 32768

#define QKV_BUF 20480   // per buffer: 12288 W + 8192 X
#define QKV_XB  12288

typedef __attribute__((ext_vector_type(4)))  float f32x4;
typedef __attribute__((ext_vector_type(16))) float f32x16;
typedef __attribute__((ext_vector_type(8)))  short s16x8;   // bf16x8 MFMA fragment
typedef __attribute__((ext_vector_type(4)))  float vfloat4;

__device__ __forceinline__ unsigned short f2bf(float x) {
  return __builtin_bit_cast(unsigned short, __float2bfloat16(x));
}
__device__ __forceinline__ unsigned pkbf(float lo, float hi) {
  return (unsigned)f2bf(lo) | ((unsigned)f2bf(hi) << 16);
}

union ABFrag { s16x8 v; unsigned d[4]; };

__device__ __forceinline__ void gl_lds16(const void* g, const unsigned char* l) {
  __builtin_amdgcn_global_load_lds(
      (const __attribute__((address_space(1))) unsigned int*)(g),
      (__attribute__((address_space(3))) unsigned int*)(l), 16, 0, 0);
}

// ---------------- kernel 0: weight transpose+cast, per-chunk layout ----
__global__ __launch_bounds__(256) void wt_kernel(const float* __restrict__ Wk,
                                                 const float* __restrict__ Wq,
                                                 const float* __restrict__ Wv,
                                                 unsigned short* __restrict__ wT2) {
  int gid = blockIdx.x * 256 + threadIdx.x;   // 0..196607
  int j = gid & 7;
  int t1 = gid >> 3;          // 0..24575
  int sk = t1 % 768;
  int c  = t1 / 768;          // 0..31
  int g = sk / 192, n = sk % 192;
  int k = c * 32 + g * 8 + j;
  const float* W = (n < 64) ? Wq : (n < 128) ? Wk : Wv;
  float s = (n < 64) ? 0.18033688011112042f : 1.0f;  // 0.125 * log2(e)
  wT2[gid] = f2bf(W[k * 64 + (n & 63)] * s);
}

// ---------------- kernel 1: fused QKV projection v8 ----------------
// Block 256 thd = 4 waves, 64 rows (16/wave), all 192 cols. 32 phases, K=32.
// Double buffer (c&1), issue c+2 after compute, vmcnt(5); tail 5/0.
// 40KB LDS + VGPR<=128 -> 4 blocks/CU = 4 waves/SIMD (TLP latency hiding).
__global__ __launch_bounds__(256, 4) void qkv_kernel(const float* __restrict__ x,
                                                     const unsigned short* __restrict__ wT2,
                                                     unsigned short* __restrict__ q_ws,
                                                     unsigned short* __restrict__ k_ws,
                                                     unsigned short* __restrict__ vT) {
  __shared__ __align__(16) unsigned char smem[2 * QKV_BUF];  // 40960 B
  const int t = threadIdx.x;
  const int w = t >> 6, lane = t & 63;
  const int g = lane >> 4, nn = lane & 15;
  const int m0blk = blockIdx.x * 64;
  const int m0 = m0blk + w * 16;

  f32x4 acc[12];
#pragma unroll
  for (int i = 0; i < 12; ++i) acc[i] = f32x4{0.f, 0.f, 0.f, 0.f};

  // ---- staging sources ----
  const unsigned short* wsrcA = wT2 + (size_t)(w * 192 + lane) * 8;  // +c*6144
  const int wd0 = w * 3072;                                          // +p*1024
  const float* xs0 = x + (size_t)(m0blk + w * 16 + 0 + (lane >> 3)) * NE + (lane & 7) * 4;
  const float* xs1 = x + (size_t)(m0blk + w * 16 + 8 + (lane >> 3)) * NE + (lane & 7) * 4;
  const int xd0 = QKV_XB + w * 2048;
  const int xd1 = xd0 + 1024;

  // ---- read offsets ----
  const int abase = QKV_XB + (w * 16 + nn) * 128 + g * 32;
  const int wbase = (g * 192 + nn) * 16;

#define ISSUE(C)                                                               \
  {                                                                            \
    unsigned char* db_ = smem + ((C) & 1) * QKV_BUF;                           \
    gl_lds16(wsrcA + (size_t)(C) * 6144, db_ + wd0);                           \
    gl_lds16(wsrcA + (size_t)(C) * 6144 + 512, db_ + wd0 + 1024);              \
    gl_lds16(wsrcA + (size_t)(C) * 6144 + 1024, db_ + wd0 + 2048);             \
    gl_lds16(xs0 + (C) * 32, db_ + xd0);                                       \
    gl_lds16(xs1 + (C) * 32, db_ + xd1);                                       \
  }

  // ---- prologue: clusters 0,1 in order ----
  ISSUE(0)
  __builtin_amdgcn_sched_barrier(0);
  ISSUE(1)
  __builtin_amdgcn_sched_barrier(0);

#define PHASE(C, VM, DOISS)                                                    \
  {                                                                            \
    asm volatile("s_waitcnt vmcnt(" #VM ")" ::: "memory");                     \
    __builtin_amdgcn_s_barrier();                                              \
    __builtin_amdgcn_sched_barrier(0);                                         \
    const unsigned char* bb_ = smem + ((C) & 1) * QKV_BUF;                     \
    const vfloat4 a0_ = *(const vfloat4*)(bb_ + abase);                        \
    const vfloat4 a1_ = *(const vfloat4*)(bb_ + abase + 16);                   \
    ABFrag af;                                                                 \
    af.d[0] = pkbf(a0_.x, a0_.y); af.d[1] = pkbf(a0_.z, a0_.w);                \
    af.d[2] = pkbf(a1_.x, a1_.y); af.d[3] = pkbf(a1_.z, a1_.w);                \
    _Pragma("unroll")                                                          \
    for (int i = 0; i < 12; ++i) {                                             \
      const s16x8 bf = *(const s16x8*)(bb_ + wbase + i * 256);                 \
      acc[i] = __builtin_amdgcn_mfma_f32_16x16x32_bf16(af.v, bf, acc[i], 0, 0, 0); \
    }                                                                          \
    __builtin_amdgcn_sched_barrier(0);                                         \
    __builtin_amdgcn_s_barrier();                                              \
    __builtin_amdgcn_sched_barrier(0);                                         \
    if (DOISS) { ISSUE((C) + 2) }                                              \
    __builtin_amdgcn_sched_barrier(0);                                         \
  }

#pragma unroll
  for (int c = 0; c < 30; ++c) PHASE(c, 5, 1)
  PHASE(30, 5, 0)
  PHASE(31, 0, 0)
#undef PHASE
#undef ISSUE

  // ---- epilogue: D row = m0 + 4g + j, col = 16i + nn ----
  const int rbase = m0 + 4 * g;
#pragma unroll
  for (int i = 0; i < 12; ++i) {
    const int c = 16 * i + nn;
#pragma unroll
    for (int j = 0; j < 4; ++j) {
      const int rr = rbase + j;
      const unsigned short h = f2bf(acc[i][j]);
      if (c < 64) {
        q_ws[(size_t)rr * HS + c] = h;
      } else if (c < 128) {
        k_ws[(size_t)rr * HS + (c - 64)] = h;
      } else {
        const int b = rr >> 12, tt = rr & 4095;
        vT[((size_t)(b * HS + (c - 128))) * TS + tt] = h;
      }
    }
  }
}

// ---------------- kernel 2: causal flash attention, 32x32 lane-local -------
// S^T(32kv x 32q) = sum_kk mfma32x32x16(K-frag, Q^T-frag). Lane (qi,hi) holds
// st_[r] = S^T[kv=(r&3)+8*(r>>2)+4hi][q=qi]; the other 16 kv live in lane^32.
// Reduces and P^T B-frag assembly use __shfl_xor(...,32).
#define TILE32(S0, DIAG, QF, M_RUN, L_RUN, O)                                  \
  {                                                                            \
    const int s0_ = (S0);                                                      \
    const unsigned short* kr_ = kptr + (size_t)(s0_ + qi) * HS + hi8;          \
    const s16x8 ka0_ = *(const s16x8*)(kr_);                                   \
    const s16x8 ka1_ = *(const s16x8*)(kr_ + 16);                              \
    const s16x8 ka2_ = *(const s16x8*)(kr_ + 32);                              \
    const s16x8 ka3_ = *(const s16x8*)(kr_ + 48);                              \
    const unsigned short* vr0_ = vptr + (size_t)qi * TS + s0_ + hi8;           \
    const unsigned short* vr1_ = vptr + (size_t)(32 + qi) * TS + s0_ + hi8;    \
    f32x16 st_;                                                                \
    _Pragma("unroll") for (int r = 0; r < 16; ++r) st_[r] = 0.f;               \
    st_ = __builtin_amdgcn_mfma_f32_32x32x16_bf16(ka0_, QF[0], st_, 0, 0, 0);  \
    st_ = __builtin_amdgcn_mfma_f32_32x32x16_bf16(ka1_, QF[1], st_, 0, 0, 0);  \
    st_ = __builtin_amdgcn_mfma_f32_32x32x16_bf16(ka2_, QF[2], st_, 0, 0, 0);  \
    st_ = __builtin_amdgcn_mfma_f32_32x32x16_bf16(ka3_, QF[3], st_, 0, 0, 0);  \
    if (DIAG) {                                                                \
      _Pragma("unroll") for (int r = 0; r < 16; ++r) {                         \
        const int kvl_ = (r & 3) + 8 * (r >> 2) + hi4;                         \
        if (kvl_ > qi) st_[r] = -1e30f;                                        \
      }                                                                        \
    }                                                                          \
    float mx_ =                                                                \
      fmaxf(fmaxf(fmaxf(fmaxf(st_[0], st_[1]), fmaxf(st_[2], st_[3])),         \
                  fmaxf(fmaxf(st_[4], st_[5]), fmaxf(st_[6], st_[7]))),        \
            fmaxf(fmaxf(fmaxf(st_[8], st_[9]), fmaxf(st_[10], st_[11])),       \
                  fmaxf(fmaxf(st_[12], st_[13]), fmaxf(st_[14], st_[15]))));   \
    mx_ = fmaxf(mx_, __shfl_xor(mx_, 32, 64));                                 \
    const float mn_ = fmaxf(M_RUN, mx_);                                       \
    if (__ballot(mn_ > M_RUN)) {                                               \
      const float fs_ = __builtin_amdgcn_exp2f(M_RUN - mn_);                   \
      _Pragma("unroll") for (int r = 0; r < 16; ++r) {                         \
        O[0][r] *= fs_; O[1][r] *= fs_;                                        \
      }                                                                        \
      L_RUN *= fs_;                                                            \
      M_RUN = mn_;                                                             \
    }                                                                          \
    float p_[16];                                                              \
    _Pragma("unroll") for (int r = 0; r < 16; ++r)                             \
      p_[r] = __builtin_amdgcn_exp2f(st_[r] - M_RUN);                          \
    float sm_ = ((p_[0] + p_[1]) + (p_[2] + p_[3])) +                          \
                ((p_[4] + p_[5]) + (p_[6] + p_[7]));                           \
    sm_ += ((p_[8] + p_[9]) + (p_[10] + p_[11])) +                             \
           ((p_[12] + p_[13]) + (p_[14] + p_[15]));                            \
    sm_ += __shfl_xor(sm_, 32, 64);                                            \
    L_RUN += sm_;                                                              \
    const unsigned q01_ = pkbf(p_[0], p_[1]),   q23_ = pkbf(p_[2], p_[3]);     \
    const unsigned q45_ = pkbf(p_[4], p_[5]),   q67_ = pkbf(p_[6], p_[7]);     \
    const unsigned q89_ = pkbf(p_[8], p_[9]),   qab_ = pkbf(p_[10], p_[11]);   \
    const unsigned qcd_ = pkbf(p_[12], p_[13]), qef_ = pkbf(p_[14], p_[15]);   \
    const unsigned t01_ = (unsigned)__shfl_xor((int)q01_, 32, 64);             \
    const unsigned t23_ = (unsigned)__shfl_xor((int)q23_, 32, 64);             \
    const unsigned t45_ = (unsigned)__shfl_xor((int)q45_, 32, 64);             \
    const unsigned t67_ = (unsigned)__shfl_xor((int)q67_, 32, 64);             \
    const unsigned t89_ = (unsigned)__shfl_xor((int)q89_, 32, 64);             \
    const unsigned tab_ = (unsigned)__shfl_xor((int)qab_, 32, 64);             \
    const unsigned tcd_ = (unsigned)__shfl_xor((int)qcd_, 32, 64);             \
    const unsigned tef_ = (unsigned)__shfl_xor((int)qef_, 32, 64);             \
    ABFrag pf0_, pf1_;                                                         \
    pf0_.d[0] = hi ? t45_ : q01_;                                              \
    pf0_.d[1] = hi ? t67_ : q23_;                                              \
    pf0_.d[2] = hi ? q45_ : t01_;                                              \
    pf0_.d[3] = hi ? q67_ : t23_;                                              \
    pf1_.d[0] = hi ? tcd_ : q89_;                                              \
    pf1_.d[1] = hi ? tef_ : qab_;                                              \
    pf1_.d[2] = hi ? qcd_ : t89_;                                              \
    pf1_.d[3] = hi ? qef_ : tab_;                                              \
    const s16x8 vf00_ = *(const s16x8*)(vr0_);                                 \
    const s16x8 vf01_ = *(const s16x8*)(vr0_ + 16);                            \
    const s16x8 vf10_ = *(const s16x8*)(vr1_);                                 \
    const s16x8 vf11_ = *(const s16x8*)(vr1_ + 16);                            \
    O[0] = __builtin_amdgcn_mfma_f32_32x32x16_bf16(vf00_, pf0_.v, O[0], 0,0,0);\
    O[0] = __builtin_amdgcn_mfma_f32_32x32x16_bf16(vf01_, pf1_.v, O[0], 0,0,0);\
    O[1] = __builtin_amdgcn_mfma_f32_32x32x16_bf16(vf10_, pf0_.v, O[1], 0,0,0);\
    O[1] = __builtin_amdgcn_mfma_f32_32x32x16_bf16(vf11_, pf1_.v, O[1], 0,0,0);\
  }

__global__ __launch_bounds__(256, 2) void attn_kernel(const unsigned short* __restrict__ q_ws,
                                                      const unsigned short* __restrict__ k_ws,
                                                      const unsigned short* __restrict__ vT,
                                                      float* __restrict__ out) {
  __shared__ float o_sm[4][32][68];    // shared scratch, reused for A then B
  __shared__ float lm_sm[4][32][2];

  const int wv = threadIdx.x >> 6, lane = threadIdx.x & 63;
  const int qi = lane & 31, hi = lane >> 5;
  const int hi8 = 8 * hi, hi4 = 4 * hi;

  const int bid = blockIdx.x;             // 0..511
  const int b = bid & 7;                  // batch <-> XCD alignment
  const int pr = bid >> 3;                // 0..63
  const int tiA = pr, tiB = 127 - pr;     // paired long/short 32-row tiles
  const int t0A = tiA * 32, t0B = tiB * 32;

  const unsigned short* kptr = k_ws + (size_t)b * TS * HS;
  const unsigned short* vptr = vT + (size_t)b * HS * TS;
  const unsigned short* qrA = q_ws + (size_t)(b * TS + t0A + qi) * HS + hi8;
  const unsigned short* qrB = q_ws + (size_t)(b * TS + t0B + qi) * HS + hi8;

  s16x8 qfA[4], qfB[4];
#pragma unroll
  for (int kk = 0; kk < 4; ++kk) {
    qfA[kk] = *(const s16x8*)(qrA + 16 * kk);
    qfB[kk] = *(const s16x8*)(qrB + 16 * kk);
  }

  f32x16 oA[2], oB[2];
#pragma unroll
  for (int r = 0; r < 16; ++r) { oA[0][r] = 0.f; oA[1][r] = 0.f; oB[0][r] = 0.f; oB[1][r] = 0.f; }
  float mA = -1e30f, lA = 0.f, mB = -1e30f, lB = 0.f;

  const int ntA = tiA + 1, ntB = tiB + 1;
  for (int it = wv; it < ntB; it += 4) {
    const int s0 = it * 32;
    if (it < ntA) TILE32(s0, it == tiA, qfA, mA, lA, oA)
    TILE32(s0, it == tiB, qfB, mB, lB, oB)
  }

  const int q = threadIdx.x >> 3;         // 0..31
  const int h0 = (threadIdx.x & 7) * 8;   // 0..56

  // ---- tile A: partials -> LDS, merge, store ----
#pragma unroll
  for (int ht = 0; ht < 2; ++ht)
#pragma unroll
    for (int r = 0; r < 16; ++r)
      o_sm[wv][qi][ht * 32 + (r & 3) + 8 * (r >> 2) + hi4] = oA[ht][r];
  if (lane < 32) { lm_sm[wv][lane][0] = mA; lm_sm[wv][lane][1] = lA; }
  __syncthreads();
  {
    const float m0v = lm_sm[0][q][0], m1v = lm_sm[1][q][0];
    const float m2v = lm_sm[2][q][0], m3v = lm_sm[3][q][0];
    const float M = fmaxf(fmaxf(m0v, m1v), fmaxf(m2v, m3v));
    const float w0 = __builtin_amdgcn_exp2f(m0v - M);
    const float w1 = __builtin_amdgcn_exp2f(m1v - M);
    const float w2 = __builtin_amdgcn_exp2f(m2v - M);
    const float w3 = __builtin_amdgcn_exp2f(m3v - M);
    const float L = w0 * lm_sm[0][q][1] + w1 * lm_sm[1][q][1] +
                    w2 * lm_sm[2][q][1] + w3 * lm_sm[3][q][1];
    const float inv = 1.0f / L;
    float rv[8];
#pragma unroll
    for (int j = 0; j < 8; ++j)
      rv[j] = (w0 * o_sm[0][q][h0 + j] + w1 * o_sm[1][q][h0 + j] +
               w2 * o_sm[2][q][h0 + j] + w3 * o_sm[3][q][h0 + j]) * inv;
    float* ob = out + ((size_t)(b * TS + t0A + q)) * HS + h0;
    *(float4*)(ob)     = float4{rv[0], rv[1], rv[2], rv[3]};
    *(float4*)(ob + 4) = float4{rv[4], rv[5], rv[6], rv[7]};
  }
  __syncthreads();

  // ---- tile B: partials -> LDS (reuse), merge, store ----
#pragma unroll
  for (int ht = 0; ht < 2; ++ht)
#pragma unroll
    for (int r = 0; r < 16; ++r)
      o_sm[wv][qi][ht * 32 + (r & 3) + 8 * (r >> 2) + hi4] = oB[ht][r];
  if (lane < 32) { lm_sm[wv][lane][0] = mB; lm_sm[wv][lane][1] = lB; }
  __syncthreads();
  {
    const float m0v = lm_sm[0][q][0], m1v = lm_sm[1][q][0];
    const float m2v = lm_sm[2][q][0], m3v = lm_sm[3][q][0];
    const float M = fmaxf(fmaxf(m0v, m1v), fmaxf(m2v, m3v));
    const float w0 = __builtin_amdgcn_exp2f(m0v - M);
    const float w1 = __builtin_amdgcn_exp2f(m1v - M);
    const float w2 = __builtin_amdgcn_exp2f(m2v - M);
    const float w3 = __builtin_amdgcn_exp2f(m3v - M);
    const float L = w0 * lm_sm[0][q][1] + w1 * lm_sm[1][q][1] +
                    w2 * lm_sm[2][q][1] + w3 * lm_sm[3][q][1];
    const float inv = 1.0f / L;
    float rv[8];
#pragma unroll
    for (int j = 0; j < 8; ++j)
      rv[j] = (w0 * o_sm[0][q][h0 + j] + w1 * o_sm[1][q][h0 + j] +
               w2 * o_sm[2][q][h0 + j] + w3 * o_sm[3][q][h0 + j]) * inv;
    float* ob = out + ((size_t)(b * TS + t0B + q)) * HS + h0;
    *(float4*)(ob)     = float4{rv[0], rv[1], rv[2], rv[3]};
    *(float4*)(ob + 4) = float4{rv[4], rv[5], rv[6], rv[7]};
  }
}

extern "C" void kernel_launch(void* const* d_in, const int* in_sizes, int n_in,
                              void* d_out, int out_size, void* d_ws, size_t ws_size,
                              hipStream_t stream) {
  const float* x  = (const float*)d_in[0];
  const float* Wk = (const float*)d_in[1];
  const float* Wq = (const float*)d_in[2];
  const float* Wv = (const float*)d_in[3];
  float* out = (float*)d_out;

  unsigned short* wT2  = (unsigned short*)d_ws;
  unsigned short* q_ws = wT2 + 192 * 1024;
  unsigned short* k_ws = q_ws + (size_t)NROW * HS;
  unsigned short* vT   = k_ws + (size_t)NROW * HS;

  wt_kernel<<<dim3(768), dim3(256), 0, stream>>>(Wk, Wq, Wv, wT2);
  qkv_kernel<<<dim3(NROW / 64), dim3(256), 0, stream>>>(x, wT2, q_ws, k_ws, vT);
  attn_kernel<<<dim3(512), dim3(256), 0, stream>>>(q_ws, k_ws, vT, out);
}

// Round 19
// 96.848 us; speedup vs baseline: 1.1124x; 1.0260x over previous
//
#include <hip/hip_runtime.h>
#include <hip/hip_bf16.h>

// Head: k/q/v projection + causal softmax attention, single head.
// B=8, T=4096, C=1024, H=64. All inputs fp32; output fp32.
//   k0: wT2 = [Wq|Wk|Wv]^T per-chunk staged layout (q cols pre-scaled).
//   k1: qkv v8 (R17-verified ~20-25us): double-buffered gl_lds pipeline,
//       vmcnt(5), 32 phases of K=32, 40KB LDS -> 4 blocks/CU.
//   k2: flash attention, R8-measured-good version (49.4us): 32x32x16
//       swapped-operand, lane-local softmax, shfl_xor(32), paired
//       (ti,127-ti) tiles, 4-way KV split, PARALLEL dual-scratch merge
//       (72KB, one barrier). R17/R18's sequential 36KB merge cost ~24us
//       (oB live across tile-A merge epilogue) — reverted.

#define HS 64
#define NE 1024
#define NB 8
#define TS 4096
#define NROW (NB * TS)  // 32768

#define QKV_BUF 20480   // per buffer: 12288 W + 8192 X
#define QKV_XB  12288

typedef __attribute__((ext_vector_type(4)))  float f32x4;
typedef __attribute__((ext_vector_type(16))) float f32x16;
typedef __attribute__((ext_vector_type(8)))  short s16x8;   // bf16x8 MFMA fragment
typedef __attribute__((ext_vector_type(4)))  float vfloat4;

__device__ __forceinline__ unsigned short f2bf(float x) {
  return __builtin_bit_cast(unsigned short, __float2bfloat16(x));
}
__device__ __forceinline__ unsigned pkbf(float lo, float hi) {
  return (unsigned)f2bf(lo) | ((unsigned)f2bf(hi) << 16);
}

union ABFrag { s16x8 v; unsigned d[4]; };

__device__ __forceinline__ void gl_lds16(const void* g, const unsigned char* l) {
  __builtin_amdgcn_global_load_lds(
      (const __attribute__((address_space(1))) unsigned int*)(g),
      (__attribute__((address_space(3))) unsigned int*)(l), 16, 0, 0);
}

// ---------------- kernel 0: weight transpose+cast, per-chunk layout ----
__global__ __launch_bounds__(256) void wt_kernel(const float* __restrict__ Wk,
                                                 const float* __restrict__ Wq,
                                                 const float* __restrict__ Wv,
                                                 unsigned short* __restrict__ wT2) {
  int gid = blockIdx.x * 256 + threadIdx.x;   // 0..196607
  int j = gid & 7;
  int t1 = gid >> 3;          // 0..24575
  int sk = t1 % 768;
  int c  = t1 / 768;          // 0..31
  int g = sk / 192, n = sk % 192;
  int k = c * 32 + g * 8 + j;
  const float* W = (n < 64) ? Wq : (n < 128) ? Wk : Wv;
  float s = (n < 64) ? 0.18033688011112042f : 1.0f;  // 0.125 * log2(e)
  wT2[gid] = f2bf(W[k * 64 + (n & 63)] * s);
}

// ---------------- kernel 1: fused QKV projection v8 ----------------
// Block 256 thd = 4 waves, 64 rows (16/wave), all 192 cols. 32 phases, K=32.
// Double buffer (c&1), issue c+2 after compute, vmcnt(5); tail 5/0.
__global__ __launch_bounds__(256, 4) void qkv_kernel(const float* __restrict__ x,
                                                     const unsigned short* __restrict__ wT2,
                                                     unsigned short* __restrict__ q_ws,
                                                     unsigned short* __restrict__ k_ws,
                                                     unsigned short* __restrict__ vT) {
  __shared__ __align__(16) unsigned char smem[2 * QKV_BUF];  // 40960 B
  const int t = threadIdx.x;
  const int w = t >> 6, lane = t & 63;
  const int g = lane >> 4, nn = lane & 15;
  const int m0blk = blockIdx.x * 64;
  const int m0 = m0blk + w * 16;

  f32x4 acc[12];
#pragma unroll
  for (int i = 0; i < 12; ++i) acc[i] = f32x4{0.f, 0.f, 0.f, 0.f};

  const unsigned short* wsrcA = wT2 + (size_t)(w * 192 + lane) * 8;  // +c*6144
  const int wd0 = w * 3072;                                          // +p*1024
  const float* xs0 = x + (size_t)(m0blk + w * 16 + 0 + (lane >> 3)) * NE + (lane & 7) * 4;
  const float* xs1 = x + (size_t)(m0blk + w * 16 + 8 + (lane >> 3)) * NE + (lane & 7) * 4;
  const int xd0 = QKV_XB + w * 2048;
  const int xd1 = xd0 + 1024;

  const int abase = QKV_XB + (w * 16 + nn) * 128 + g * 32;
  const int wbase = (g * 192 + nn) * 16;

#define ISSUE(C)                                                               \
  {                                                                            \
    unsigned char* db_ = smem + ((C) & 1) * QKV_BUF;                           \
    gl_lds16(wsrcA + (size_t)(C) * 6144, db_ + wd0);                           \
    gl_lds16(wsrcA + (size_t)(C) * 6144 + 512, db_ + wd0 + 1024);              \
    gl_lds16(wsrcA + (size_t)(C) * 6144 + 1024, db_ + wd0 + 2048);             \
    gl_lds16(xs0 + (C) * 32, db_ + xd0);                                       \
    gl_lds16(xs1 + (C) * 32, db_ + xd1);                                       \
  }

  ISSUE(0)
  __builtin_amdgcn_sched_barrier(0);
  ISSUE(1)
  __builtin_amdgcn_sched_barrier(0);

#define PHASE(C, VM, DOISS)                                                    \
  {                                                                            \
    asm volatile("s_waitcnt vmcnt(" #VM ")" ::: "memory");                     \
    __builtin_amdgcn_s_barrier();                                              \
    __builtin_amdgcn_sched_barrier(0);                                         \
    const unsigned char* bb_ = smem + ((C) & 1) * QKV_BUF;                     \
    const vfloat4 a0_ = *(const vfloat4*)(bb_ + abase);                        \
    const vfloat4 a1_ = *(const vfloat4*)(bb_ + abase + 16);                   \
    ABFrag af;                                                                 \
    af.d[0] = pkbf(a0_.x, a0_.y); af.d[1] = pkbf(a0_.z, a0_.w);                \
    af.d[2] = pkbf(a1_.x, a1_.y); af.d[3] = pkbf(a1_.z, a1_.w);                \
    _Pragma("unroll")                                                          \
    for (int i = 0; i < 12; ++i) {                                             \
      const s16x8 bf = *(const s16x8*)(bb_ + wbase + i * 256);                 \
      acc[i] = __builtin_amdgcn_mfma_f32_16x16x32_bf16(af.v, bf, acc[i], 0, 0, 0); \
    }                                                                          \
    __builtin_amdgcn_sched_barrier(0);                                         \
    __builtin_amdgcn_s_barrier();                                              \
    __builtin_amdgcn_sched_barrier(0);                                         \
    if (DOISS) { ISSUE((C) + 2) }                                              \
    __builtin_amdgcn_sched_barrier(0);                                         \
  }

#pragma unroll
  for (int c = 0; c < 30; ++c) PHASE(c, 5, 1)
  PHASE(30, 5, 0)
  PHASE(31, 0, 0)
#undef PHASE
#undef ISSUE

  const int rbase = m0 + 4 * g;
#pragma unroll
  for (int i = 0; i < 12; ++i) {
    const int c = 16 * i + nn;
#pragma unroll
    for (int j = 0; j < 4; ++j) {
      const int rr = rbase + j;
      const unsigned short h = f2bf(acc[i][j]);
      if (c < 64) {
        q_ws[(size_t)rr * HS + c] = h;
      } else if (c < 128) {
        k_ws[(size_t)rr * HS + (c - 64)] = h;
      } else {
        const int b = rr >> 12, tt = rr & 4095;
        vT[((size_t)(b * HS + (c - 128))) * TS + tt] = h;
      }
    }
  }
}

// ---------------- kernel 2: causal flash attention, 32x32 lane-local -------
// S^T(32kv x 32q) = sum_kk mfma32x32x16(K-frag, Q^T-frag). Lane (qi,hi) holds
// st_[r] = S^T[kv=(r&3)+8*(r>>2)+4hi][q=qi]; the other 16 kv live in lane^32.
// Reduces and P^T B-frag assembly use __shfl_xor(...,32).
#define TILE32(S0, DIAG, QF, M_RUN, L_RUN, O)                                  \
  {                                                                            \
    const int s0_ = (S0);                                                      \
    const unsigned short* kr_ = kptr + (size_t)(s0_ + qi) * HS + hi8;          \
    const s16x8 ka0_ = *(const s16x8*)(kr_);                                   \
    const s16x8 ka1_ = *(const s16x8*)(kr_ + 16);                              \
    const s16x8 ka2_ = *(const s16x8*)(kr_ + 32);                              \
    const s16x8 ka3_ = *(const s16x8*)(kr_ + 48);                              \
    const unsigned short* vr0_ = vptr + (size_t)qi * TS + s0_ + hi8;           \
    const unsigned short* vr1_ = vptr + (size_t)(32 + qi) * TS + s0_ + hi8;    \
    f32x16 st_;                                                                \
    _Pragma("unroll") for (int r = 0; r < 16; ++r) st_[r] = 0.f;               \
    st_ = __builtin_amdgcn_mfma_f32_32x32x16_bf16(ka0_, QF[0], st_, 0, 0, 0);  \
    st_ = __builtin_amdgcn_mfma_f32_32x32x16_bf16(ka1_, QF[1], st_, 0, 0, 0);  \
    st_ = __builtin_amdgcn_mfma_f32_32x32x16_bf16(ka2_, QF[2], st_, 0, 0, 0);  \
    st_ = __builtin_amdgcn_mfma_f32_32x32x16_bf16(ka3_, QF[3], st_, 0, 0, 0);  \
    if (DIAG) {                                                                \
      _Pragma("unroll") for (int r = 0; r < 16; ++r) {                         \
        const int kvl_ = (r & 3) + 8 * (r >> 2) + hi4;                         \
        if (kvl_ > qi) st_[r] = -1e30f;                                        \
      }                                                                        \
    }                                                                          \
    float mx_ =                                                                \
      fmaxf(fmaxf(fmaxf(fmaxf(st_[0], st_[1]), fmaxf(st_[2], st_[3])),         \
                  fmaxf(fmaxf(st_[4], st_[5]), fmaxf(st_[6], st_[7]))),        \
            fmaxf(fmaxf(fmaxf(st_[8], st_[9]), fmaxf(st_[10], st_[11])),       \
                  fmaxf(fmaxf(st_[12], st_[13]), fmaxf(st_[14], st_[15]))));   \
    mx_ = fmaxf(mx_, __shfl_xor(mx_, 32, 64));                                 \
    const float mn_ = fmaxf(M_RUN, mx_);                                       \
    if (__ballot(mn_ > M_RUN)) {                                               \
      const float fs_ = __builtin_amdgcn_exp2f(M_RUN - mn_);                   \
      _Pragma("unroll") for (int r = 0; r < 16; ++r) {                         \
        O[0][r] *= fs_; O[1][r] *= fs_;                                        \
      }                                                                        \
      L_RUN *= fs_;                                                            \
      M_RUN = mn_;                                                             \
    }                                                                          \
    float p_[16];                                                              \
    _Pragma("unroll") for (int r = 0; r < 16; ++r)                             \
      p_[r] = __builtin_amdgcn_exp2f(st_[r] - M_RUN);                          \
    float sm_ = ((p_[0] + p_[1]) + (p_[2] + p_[3])) +                          \
                ((p_[4] + p_[5]) + (p_[6] + p_[7]));                           \
    sm_ += ((p_[8] + p_[9]) + (p_[10] + p_[11])) +                             \
           ((p_[12] + p_[13]) + (p_[14] + p_[15]));                            \
    sm_ += __shfl_xor(sm_, 32, 64);                                            \
    L_RUN += sm_;                                                              \
    const unsigned q01_ = pkbf(p_[0], p_[1]),   q23_ = pkbf(p_[2], p_[3]);     \
    const unsigned q45_ = pkbf(p_[4], p_[5]),   q67_ = pkbf(p_[6], p_[7]);     \
    const unsigned q89_ = pkbf(p_[8], p_[9]),   qab_ = pkbf(p_[10], p_[11]);   \
    const unsigned qcd_ = pkbf(p_[12], p_[13]), qef_ = pkbf(p_[14], p_[15]);   \
    const unsigned t01_ = (unsigned)__shfl_xor((int)q01_, 32, 64);             \
    const unsigned t23_ = (unsigned)__shfl_xor((int)q23_, 32, 64);             \
    const unsigned t45_ = (unsigned)__shfl_xor((int)q45_, 32, 64);             \
    const unsigned t67_ = (unsigned)__shfl_xor((int)q67_, 32, 64);             \
    const unsigned t89_ = (unsigned)__shfl_xor((int)q89_, 32, 64);             \
    const unsigned tab_ = (unsigned)__shfl_xor((int)qab_, 32, 64);             \
    const unsigned tcd_ = (unsigned)__shfl_xor((int)qcd_, 32, 64);             \
    const unsigned tef_ = (unsigned)__shfl_xor((int)qef_, 32, 64);             \
    ABFrag pf0_, pf1_;                                                         \
    pf0_.d[0] = hi ? t45_ : q01_;                                              \
    pf0_.d[1] = hi ? t67_ : q23_;                                              \
    pf0_.d[2] = hi ? q45_ : t01_;                                              \
    pf0_.d[3] = hi ? q67_ : t23_;                                              \
    pf1_.d[0] = hi ? tcd_ : q89_;                                              \
    pf1_.d[1] = hi ? tef_ : qab_;                                              \
    pf1_.d[2] = hi ? qcd_ : t89_;                                              \
    pf1_.d[3] = hi ? qef_ : tab_;                                              \
    const s16x8 vf00_ = *(const s16x8*)(vr0_);                                 \
    const s16x8 vf01_ = *(const s16x8*)(vr0_ + 16);                            \
    const s16x8 vf10_ = *(const s16x8*)(vr1_);                                 \
    const s16x8 vf11_ = *(const s16x8*)(vr1_ + 16);                            \
    O[0] = __builtin_amdgcn_mfma_f32_32x32x16_bf16(vf00_, pf0_.v, O[0], 0,0,0);\
    O[0] = __builtin_amdgcn_mfma_f32_32x32x16_bf16(vf01_, pf1_.v, O[0], 0,0,0);\
    O[1] = __builtin_amdgcn_mfma_f32_32x32x16_bf16(vf10_, pf0_.v, O[1], 0,0,0);\
    O[1] = __builtin_amdgcn_mfma_f32_32x32x16_bf16(vf11_, pf1_.v, O[1], 0,0,0);\
  }

__global__ __launch_bounds__(256, 2) void attn_kernel(const unsigned short* __restrict__ q_ws,
                                                      const unsigned short* __restrict__ k_ws,
                                                      const unsigned short* __restrict__ vT,
                                                      float* __restrict__ out) {
  __shared__ float o_sm[2][4][32][68];   // [tile][wave][q][h] padded
  __shared__ float lm_sm[2][4][32][2];

  const int wv = threadIdx.x >> 6, lane = threadIdx.x & 63;
  const int qi = lane & 31, hi = lane >> 5;
  const int hi8 = 8 * hi, hi4 = 4 * hi;

  const int bid = blockIdx.x;             // 0..511
  const int b = bid & 7;                  // batch <-> XCD alignment
  const int pr = bid >> 3;                // 0..63
  const int tiA = pr, tiB = 127 - pr;     // paired long/short 32-row tiles
  const int t0A = tiA * 32, t0B = tiB * 32;

  const unsigned short* kptr = k_ws + (size_t)b * TS * HS;
  const unsigned short* vptr = vT + (size_t)b * HS * TS;
  const unsigned short* qrA = q_ws + (size_t)(b * TS + t0A + qi) * HS + hi8;
  const unsigned short* qrB = q_ws + (size_t)(b * TS + t0B + qi) * HS + hi8;

  s16x8 qfA[4], qfB[4];
#pragma unroll
  for (int kk = 0; kk < 4; ++kk) {
    qfA[kk] = *(const s16x8*)(qrA + 16 * kk);
    qfB[kk] = *(const s16x8*)(qrB + 16 * kk);
  }

  f32x16 oA[2], oB[2];
#pragma unroll
  for (int r = 0; r < 16; ++r) { oA[0][r] = 0.f; oA[1][r] = 0.f; oB[0][r] = 0.f; oB[1][r] = 0.f; }
  float mA = -1e30f, lA = 0.f, mB = -1e30f, lB = 0.f;

  const int ntA = tiA + 1, ntB = tiB + 1;
  for (int it = wv; it < ntB; it += 4) {
    const int s0 = it * 32;
    if (it < ntA) TILE32(s0, it == tiA, qfA, mA, lA, oA)
    TILE32(s0, it == tiB, qfB, mB, lB, oB)
  }

  // ---- partials to LDS ----
#pragma unroll
  for (int ht = 0; ht < 2; ++ht)
#pragma unroll
    for (int r = 0; r < 16; ++r) {
      const int h = ht * 32 + (r & 3) + 8 * (r >> 2) + hi4;
      o_sm[0][wv][qi][h] = oA[ht][r];
      o_sm[1][wv][qi][h] = oB[ht][r];
    }
  if (lane < 32) {
    lm_sm[0][wv][lane][0] = mA; lm_sm[0][wv][lane][1] = lA;
    lm_sm[1][wv][lane][0] = mB; lm_sm[1][wv][lane][1] = lB;
  }
  __syncthreads();

  // ---- merge 4 partials per tile; thread owns (q, 8 h) ----
  const int q = threadIdx.x >> 3;         // 0..31
  const int h0 = (threadIdx.x & 7) * 8;   // 0..56
  const int t0X[2] = {t0A, t0B};
#pragma unroll
  for (int X = 0; X < 2; ++X) {
    const float m0v = lm_sm[X][0][q][0], m1v = lm_sm[X][1][q][0];
    const float m2v = lm_sm[X][2][q][0], m3v = lm_sm[X][3][q][0];
    const float M = fmaxf(fmaxf(m0v, m1v), fmaxf(m2v, m3v));
    const float w0 = __builtin_amdgcn_exp2f(m0v - M);
    const float w1 = __builtin_amdgcn_exp2f(m1v - M);
    const float w2 = __builtin_amdgcn_exp2f(m2v - M);
    const float w3 = __builtin_amdgcn_exp2f(m3v - M);
    const float L = w0 * lm_sm[X][0][q][1] + w1 * lm_sm[X][1][q][1] +
                    w2 * lm_sm[X][2][q][1] + w3 * lm_sm[X][3][q][1];
    const float inv = 1.0f / L;
    float rv[8];
#pragma unroll
    for (int j = 0; j < 8; ++j)
      rv[j] = (w0 * o_sm[X][0][q][h0 + j] + w1 * o_sm[X][1][q][h0 + j] +
               w2 * o_sm[X][2][q][h0 + j] + w3 * o_sm[X][3][q][h0 + j]) * inv;
    float* ob = out + ((size_t)(b * TS + t0X[X] + q)) * HS + h0;
    *(float4*)(ob)     = float4{rv[0], rv[1], rv[2], rv[3]};
    *(float4*)(ob + 4) = float4{rv[4], rv[5], rv[6], rv[7]};
  }
}

extern "C" void kernel_launch(void* const* d_in, const int* in_sizes, int n_in,
                              void* d_out, int out_size, void* d_ws, size_t ws_size,
                              hipStream_t stream) {
  const float* x  = (const float*)d_in[0];
  const float* Wk = (const float*)d_in[1];
  const float* Wq = (const float*)d_in[2];
  const float* Wv = (const float*)d_in[3];
  float* out = (float*)d_out;

  unsigned short* wT2  = (unsigned short*)d_ws;
  unsigned short* q_ws = wT2 + 192 * 1024;
  unsigned short* k_ws = q_ws + (size_t)NROW * HS;
  unsigned short* vT   = k_ws + (size_t)NROW * HS;

  wt_kernel<<<dim3(768), dim3(256), 0, stream>>>(Wk, Wq, Wv, wT2);
  qkv_kernel<<<dim3(NROW / 64), dim3(256), 0, stream>>>(x, wT2, q_ws, k_ws, vT);
  attn_kernel<<<dim3(512), dim3(256), 0, stream>>>(q_ws, k_ws, vT, out);
}

// Round 20
// 96.753 us; speedup vs baseline: 1.1134x; 1.0010x over previous
//
#include <hip/hip_runtime.h>
#include <hip/hip_bf16.h>

// Head: k/q/v projection + causal softmax attention, single head.
// B=8, T=4096, C=1024, H=64. All inputs fp32; output fp32.
//   k0: wT2 = [Wq|Wk|Wv]^T per-chunk staged layout (q cols pre-scaled).
//   k1: qkv v8 (measured ~20-22us = HBM floor for x): double-buffered gl_lds
//       pipeline, vmcnt(5), 32 phases of K=32, 40KB LDS.
//   k2: flash attention, latency-bound at 2 waves/SIMD (R19: ~74us, ~1390
//       cyc/TILE32 vs ~800 chain). This round: merge scratch 72KB -> 36KB via
//       two-row-half PARALLEL A/B merge (3 syncs, epilogue only) -> LDS
//       admits 3 blocks/CU; + s_setprio(1) around MFMA clusters (guide T5,
//       +4-7% on barrier-free attn). No launch_bounds min-waves forcing
//       (R17: (256,3) -> pathological VGPR=84 spill).

#define HS 64
#define NE 1024
#define NB 8
#define TS 4096
#define NROW (NB * TS)  // 32768

#define QKV_BUF 20480   // per buffer: 12288 W + 8192 X
#define QKV_XB  12288

typedef __attribute__((ext_vector_type(4)))  float f32x4;
typedef __attribute__((ext_vector_type(16))) float f32x16;
typedef __attribute__((ext_vector_type(8)))  short s16x8;   // bf16x8 MFMA fragment
typedef __attribute__((ext_vector_type(4)))  float vfloat4;

__device__ __forceinline__ unsigned short f2bf(float x) {
  return __builtin_bit_cast(unsigned short, __float2bfloat16(x));
}
__device__ __forceinline__ unsigned pkbf(float lo, float hi) {
  return (unsigned)f2bf(lo) | ((unsigned)f2bf(hi) << 16);
}

union ABFrag { s16x8 v; unsigned d[4]; };

__device__ __forceinline__ void gl_lds16(const void* g, const unsigned char* l) {
  __builtin_amdgcn_global_load_lds(
      (const __attribute__((address_space(1))) unsigned int*)(g),
      (__attribute__((address_space(3))) unsigned int*)(l), 16, 0, 0);
}

// ---------------- kernel 0: weight transpose+cast, per-chunk layout ----
__global__ __launch_bounds__(256) void wt_kernel(const float* __restrict__ Wk,
                                                 const float* __restrict__ Wq,
                                                 const float* __restrict__ Wv,
                                                 unsigned short* __restrict__ wT2) {
  int gid = blockIdx.x * 256 + threadIdx.x;   // 0..196607
  int j = gid & 7;
  int t1 = gid >> 3;          // 0..24575
  int sk = t1 % 768;
  int c  = t1 / 768;          // 0..31
  int g = sk / 192, n = sk % 192;
  int k = c * 32 + g * 8 + j;
  const float* W = (n < 64) ? Wq : (n < 128) ? Wk : Wv;
  float s = (n < 64) ? 0.18033688011112042f : 1.0f;  // 0.125 * log2(e)
  wT2[gid] = f2bf(W[k * 64 + (n & 63)] * s);
}

// ---------------- kernel 1: fused QKV projection v8 ----------------
__global__ __launch_bounds__(256, 4) void qkv_kernel(const float* __restrict__ x,
                                                     const unsigned short* __restrict__ wT2,
                                                     unsigned short* __restrict__ q_ws,
                                                     unsigned short* __restrict__ k_ws,
                                                     unsigned short* __restrict__ vT) {
  __shared__ __align__(16) unsigned char smem[2 * QKV_BUF];  // 40960 B
  const int t = threadIdx.x;
  const int w = t >> 6, lane = t & 63;
  const int g = lane >> 4, nn = lane & 15;
  const int m0blk = blockIdx.x * 64;
  const int m0 = m0blk + w * 16;

  f32x4 acc[12];
#pragma unroll
  for (int i = 0; i < 12; ++i) acc[i] = f32x4{0.f, 0.f, 0.f, 0.f};

  const unsigned short* wsrcA = wT2 + (size_t)(w * 192 + lane) * 8;  // +c*6144
  const int wd0 = w * 3072;                                          // +p*1024
  const float* xs0 = x + (size_t)(m0blk + w * 16 + 0 + (lane >> 3)) * NE + (lane & 7) * 4;
  const float* xs1 = x + (size_t)(m0blk + w * 16 + 8 + (lane >> 3)) * NE + (lane & 7) * 4;
  const int xd0 = QKV_XB + w * 2048;
  const int xd1 = xd0 + 1024;

  const int abase = QKV_XB + (w * 16 + nn) * 128 + g * 32;
  const int wbase = (g * 192 + nn) * 16;

#define ISSUE(C)                                                               \
  {                                                                            \
    unsigned char* db_ = smem + ((C) & 1) * QKV_BUF;                           \
    gl_lds16(wsrcA + (size_t)(C) * 6144, db_ + wd0);                           \
    gl_lds16(wsrcA + (size_t)(C) * 6144 + 512, db_ + wd0 + 1024);              \
    gl_lds16(wsrcA + (size_t)(C) * 6144 + 1024, db_ + wd0 + 2048);             \
    gl_lds16(xs0 + (C) * 32, db_ + xd0);                                       \
    gl_lds16(xs1 + (C) * 32, db_ + xd1);                                       \
  }

  ISSUE(0)
  __builtin_amdgcn_sched_barrier(0);
  ISSUE(1)
  __builtin_amdgcn_sched_barrier(0);

#define PHASE(C, VM, DOISS)                                                    \
  {                                                                            \
    asm volatile("s_waitcnt vmcnt(" #VM ")" ::: "memory");                     \
    __builtin_amdgcn_s_barrier();                                              \
    __builtin_amdgcn_sched_barrier(0);                                         \
    const unsigned char* bb_ = smem + ((C) & 1) * QKV_BUF;                     \
    const vfloat4 a0_ = *(const vfloat4*)(bb_ + abase);                        \
    const vfloat4 a1_ = *(const vfloat4*)(bb_ + abase + 16);                   \
    ABFrag af;                                                                 \
    af.d[0] = pkbf(a0_.x, a0_.y); af.d[1] = pkbf(a0_.z, a0_.w);                \
    af.d[2] = pkbf(a1_.x, a1_.y); af.d[3] = pkbf(a1_.z, a1_.w);                \
    _Pragma("unroll")                                                          \
    for (int i = 0; i < 12; ++i) {                                             \
      const s16x8 bf = *(const s16x8*)(bb_ + wbase + i * 256);                 \
      acc[i] = __builtin_amdgcn_mfma_f32_16x16x32_bf16(af.v, bf, acc[i], 0, 0, 0); \
    }                                                                          \
    __builtin_amdgcn_sched_barrier(0);                                         \
    __builtin_amdgcn_s_barrier();                                              \
    __builtin_amdgcn_sched_barrier(0);                                         \
    if (DOISS) { ISSUE((C) + 2) }                                              \
    __builtin_amdgcn_sched_barrier(0);                                         \
  }

#pragma unroll
  for (int c = 0; c < 30; ++c) PHASE(c, 5, 1)
  PHASE(30, 5, 0)
  PHASE(31, 0, 0)
#undef PHASE
#undef ISSUE

  const int rbase = m0 + 4 * g;
#pragma unroll
  for (int i = 0; i < 12; ++i) {
    const int c = 16 * i + nn;
#pragma unroll
    for (int j = 0; j < 4; ++j) {
      const int rr = rbase + j;
      const unsigned short h = f2bf(acc[i][j]);
      if (c < 64) {
        q_ws[(size_t)rr * HS + c] = h;
      } else if (c < 128) {
        k_ws[(size_t)rr * HS + (c - 64)] = h;
      } else {
        const int b = rr >> 12, tt = rr & 4095;
        vT[((size_t)(b * HS + (c - 128))) * TS + tt] = h;
      }
    }
  }
}

// ---------------- kernel 2: causal flash attention, 32x32 lane-local -------
// S^T(32kv x 32q) = sum_kk mfma32x32x16(K-frag, Q^T-frag). Lane (qi,hi) holds
// st_[r] = S^T[kv=(r&3)+8*(r>>2)+4hi][q=qi]; the other 16 kv live in lane^32.
// Reduces and P^T B-frag assembly use __shfl_xor(...,32). setprio(1) around
// MFMA clusters (T5).
#define TILE32(S0, DIAG, QF, M_RUN, L_RUN, O)                                  \
  {                                                                            \
    const int s0_ = (S0);                                                      \
    const unsigned short* kr_ = kptr + (size_t)(s0_ + qi) * HS + hi8;          \
    const s16x8 ka0_ = *(const s16x8*)(kr_);                                   \
    const s16x8 ka1_ = *(const s16x8*)(kr_ + 16);                              \
    const s16x8 ka2_ = *(const s16x8*)(kr_ + 32);                              \
    const s16x8 ka3_ = *(const s16x8*)(kr_ + 48);                              \
    const unsigned short* vr0_ = vptr + (size_t)qi * TS + s0_ + hi8;           \
    const unsigned short* vr1_ = vptr + (size_t)(32 + qi) * TS + s0_ + hi8;    \
    f32x16 st_;                                                                \
    _Pragma("unroll") for (int r = 0; r < 16; ++r) st_[r] = 0.f;               \
    __builtin_amdgcn_s_setprio(1);                                             \
    st_ = __builtin_amdgcn_mfma_f32_32x32x16_bf16(ka0_, QF[0], st_, 0, 0, 0);  \
    st_ = __builtin_amdgcn_mfma_f32_32x32x16_bf16(ka1_, QF[1], st_, 0, 0, 0);  \
    st_ = __builtin_amdgcn_mfma_f32_32x32x16_bf16(ka2_, QF[2], st_, 0, 0, 0);  \
    st_ = __builtin_amdgcn_mfma_f32_32x32x16_bf16(ka3_, QF[3], st_, 0, 0, 0);  \
    __builtin_amdgcn_s_setprio(0);                                             \
    if (DIAG) {                                                                \
      _Pragma("unroll") for (int r = 0; r < 16; ++r) {                         \
        const int kvl_ = (r & 3) + 8 * (r >> 2) + hi4;                         \
        if (kvl_ > qi) st_[r] = -1e30f;                                        \
      }                                                                        \
    }                                                                          \
    float mx_ =                                                                \
      fmaxf(fmaxf(fmaxf(fmaxf(st_[0], st_[1]), fmaxf(st_[2], st_[3])),         \
                  fmaxf(fmaxf(st_[4], st_[5]), fmaxf(st_[6], st_[7]))),        \
            fmaxf(fmaxf(fmaxf(st_[8], st_[9]), fmaxf(st_[10], st_[11])),       \
                  fmaxf(fmaxf(st_[12], st_[13]), fmaxf(st_[14], st_[15]))));   \
    mx_ = fmaxf(mx_, __shfl_xor(mx_, 32, 64));                                 \
    const float mn_ = fmaxf(M_RUN, mx_);                                       \
    if (__ballot(mn_ > M_RUN)) {                                               \
      const float fs_ = __builtin_amdgcn_exp2f(M_RUN - mn_);                   \
      _Pragma("unroll") for (int r = 0; r < 16; ++r) {                         \
        O[0][r] *= fs_; O[1][r] *= fs_;                                        \
      }                                                                        \
      L_RUN *= fs_;                                                            \
      M_RUN = mn_;                                                             \
    }                                                                          \
    float p_[16];                                                              \
    _Pragma("unroll") for (int r = 0; r < 16; ++r)                             \
      p_[r] = __builtin_amdgcn_exp2f(st_[r] - M_RUN);                          \
    float sm_ = ((p_[0] + p_[1]) + (p_[2] + p_[3])) +                          \
                ((p_[4] + p_[5]) + (p_[6] + p_[7]));                           \
    sm_ += ((p_[8] + p_[9]) + (p_[10] + p_[11])) +                             \
           ((p_[12] + p_[13]) + (p_[14] + p_[15]));                            \
    sm_ += __shfl_xor(sm_, 32, 64);                                            \
    L_RUN += sm_;                                                              \
    const unsigned q01_ = pkbf(p_[0], p_[1]),   q23_ = pkbf(p_[2], p_[3]);     \
    const unsigned q45_ = pkbf(p_[4], p_[5]),   q67_ = pkbf(p_[6], p_[7]);     \
    const unsigned q89_ = pkbf(p_[8], p_[9]),   qab_ = pkbf(p_[10], p_[11]);   \
    const unsigned qcd_ = pkbf(p_[12], p_[13]), qef_ = pkbf(p_[14], p_[15]);   \
    const unsigned t01_ = (unsigned)__shfl_xor((int)q01_, 32, 64);             \
    const unsigned t23_ = (unsigned)__shfl_xor((int)q23_, 32, 64);             \
    const unsigned t45_ = (unsigned)__shfl_xor((int)q45_, 32, 64);             \
    const unsigned t67_ = (unsigned)__shfl_xor((int)q67_, 32, 64);             \
    const unsigned t89_ = (unsigned)__shfl_xor((int)q89_, 32, 64);             \
    const unsigned tab_ = (unsigned)__shfl_xor((int)qab_, 32, 64);             \
    const unsigned tcd_ = (unsigned)__shfl_xor((int)qcd_, 32, 64);             \
    const unsigned tef_ = (unsigned)__shfl_xor((int)qef_, 32, 64);             \
    ABFrag pf0_, pf1_;                                                         \
    pf0_.d[0] = hi ? t45_ : q01_;                                              \
    pf0_.d[1] = hi ? t67_ : q23_;                                              \
    pf0_.d[2] = hi ? q45_ : t01_;                                              \
    pf0_.d[3] = hi ? q67_ : t23_;                                              \
    pf1_.d[0] = hi ? tcd_ : q89_;                                              \
    pf1_.d[1] = hi ? tef_ : qab_;                                              \
    pf1_.d[2] = hi ? qcd_ : t89_;                                              \
    pf1_.d[3] = hi ? qef_ : tab_;                                              \
    const s16x8 vf00_ = *(const s16x8*)(vr0_);                                 \
    const s16x8 vf01_ = *(const s16x8*)(vr0_ + 16);                            \
    const s16x8 vf10_ = *(const s16x8*)(vr1_);                                 \
    const s16x8 vf11_ = *(const s16x8*)(vr1_ + 16);                            \
    __builtin_amdgcn_s_setprio(1);                                             \
    O[0] = __builtin_amdgcn_mfma_f32_32x32x16_bf16(vf00_, pf0_.v, O[0], 0,0,0);\
    O[0] = __builtin_amdgcn_mfma_f32_32x32x16_bf16(vf01_, pf1_.v, O[0], 0,0,0);\
    O[1] = __builtin_amdgcn_mfma_f32_32x32x16_bf16(vf10_, pf0_.v, O[1], 0,0,0);\
    O[1] = __builtin_amdgcn_mfma_f32_32x32x16_bf16(vf11_, pf1_.v, O[1], 0,0,0);\
    __builtin_amdgcn_s_setprio(0);                                             \
  }

__global__ __launch_bounds__(256, 2) void attn_kernel(const unsigned short* __restrict__ q_ws,
                                                      const unsigned short* __restrict__ k_ws,
                                                      const unsigned short* __restrict__ vT,
                                                      float* __restrict__ out) {
  __shared__ float o_sm[2][4][16][68];   // [tile][wave][row-half][h] 34.8KB
  __shared__ float lm_sm[2][4][32][2];   // 2KB

  const int wv = threadIdx.x >> 6, lane = threadIdx.x & 63;
  const int qi = lane & 31, hi = lane >> 5;
  const int hi8 = 8 * hi, hi4 = 4 * hi;

  const int bid = blockIdx.x;             // 0..511
  const int b = bid & 7;                  // batch <-> XCD alignment
  const int pr = bid >> 3;                // 0..63
  const int tiA = pr, tiB = 127 - pr;     // paired long/short 32-row tiles
  const int t0A = tiA * 32, t0B = tiB * 32;

  const unsigned short* kptr = k_ws + (size_t)b * TS * HS;
  const unsigned short* vptr = vT + (size_t)b * HS * TS;
  const unsigned short* qrA = q_ws + (size_t)(b * TS + t0A + qi) * HS + hi8;
  const unsigned short* qrB = q_ws + (size_t)(b * TS + t0B + qi) * HS + hi8;

  s16x8 qfA[4], qfB[4];
#pragma unroll
  for (int kk = 0; kk < 4; ++kk) {
    qfA[kk] = *(const s16x8*)(qrA + 16 * kk);
    qfB[kk] = *(const s16x8*)(qrB + 16 * kk);
  }

  f32x16 oA[2], oB[2];
#pragma unroll
  for (int r = 0; r < 16; ++r) { oA[0][r] = 0.f; oA[1][r] = 0.f; oB[0][r] = 0.f; oB[1][r] = 0.f; }
  float mA = -1e30f, lA = 0.f, mB = -1e30f, lB = 0.f;

  const int ntA = tiA + 1, ntB = tiB + 1;
  for (int it = wv; it < ntB; it += 4) {
    const int s0 = it * 32;
    if (it < ntA) TILE32(s0, it == tiA, qfA, mA, lA, oA)
    TILE32(s0, it == tiB, qfB, mB, lB, oB)
  }

  // ---- epilogue: two-row-half parallel A/B merge through 36KB scratch ----
  if (lane < 32) {
    lm_sm[0][wv][lane][0] = mA; lm_sm[0][wv][lane][1] = lA;
    lm_sm[1][wv][lane][0] = mB; lm_sm[1][wv][lane][1] = lB;
  }
  const int q8 = (threadIdx.x >> 3) & 15;   // merge row within half
  const int h0 = (threadIdx.x & 7) * 8;     // merge h-group
  const int X  = threadIdx.x >> 7;          // merge tile (0=A, 1=B)
  const int t0X = X ? t0B : t0A;

#pragma unroll
  for (int P = 0; P < 2; ++P) {
    if ((qi >> 4) == P) {
      const int qr = qi & 15;
#pragma unroll
      for (int ht = 0; ht < 2; ++ht)
#pragma unroll
        for (int r = 0; r < 16; ++r) {
          const int h = ht * 32 + (r & 3) + 8 * (r >> 2) + hi4;
          o_sm[0][wv][qr][h] = oA[ht][r];
          o_sm[1][wv][qr][h] = oB[ht][r];
        }
    }
    __syncthreads();
    {
      const int q = 16 * P + q8;
      const float m0v = lm_sm[X][0][q][0], m1v = lm_sm[X][1][q][0];
      const float m2v = lm_sm[X][2][q][0], m3v = lm_sm[X][3][q][0];
      const float M = fmaxf(fmaxf(m0v, m1v), fmaxf(m2v, m3v));
      const float w0 = __builtin_amdgcn_exp2f(m0v - M);
      const float w1 = __builtin_amdgcn_exp2f(m1v - M);
      const float w2 = __builtin_amdgcn_exp2f(m2v - M);
      const float w3 = __builtin_amdgcn_exp2f(m3v - M);
      const float L = w0 * lm_sm[X][0][q][1] + w1 * lm_sm[X][1][q][1] +
                      w2 * lm_sm[X][2][q][1] + w3 * lm_sm[X][3][q][1];
      const float inv = 1.0f / L;
      float rv[8];
#pragma unroll
      for (int j = 0; j < 8; ++j)
        rv[j] = (w0 * o_sm[X][0][q8][h0 + j] + w1 * o_sm[X][1][q8][h0 + j] +
                 w2 * o_sm[X][2][q8][h0 + j] + w3 * o_sm[X][3][q8][h0 + j]) * inv;
      float* ob = out + ((size_t)(b * TS + t0X + q)) * HS + h0;
      *(float4*)(ob)     = float4{rv[0], rv[1], rv[2], rv[3]};
      *(float4*)(ob + 4) = float4{rv[4], rv[5], rv[6], rv[7]};
    }
    if (P == 0) __syncthreads();
  }
}

extern "C" void kernel_launch(void* const* d_in, const int* in_sizes, int n_in,
                              void* d_out, int out_size, void* d_ws, size_t ws_size,
                              hipStream_t stream) {
  const float* x  = (const float*)d_in[0];
  const float* Wk = (const float*)d_in[1];
  const float* Wq = (const float*)d_in[2];
  const float* Wv = (const float*)d_in[3];
  float* out = (float*)d_out;

  unsigned short* wT2  = (unsigned short*)d_ws;
  unsigned short* q_ws = wT2 + 192 * 1024;
  unsigned short* k_ws = q_ws + (size_t)NROW * HS;
  unsigned short* vT   = k_ws + (size_t)NROW * HS;

  wt_kernel<<<dim3(768), dim3(256), 0, stream>>>(Wk, Wq, Wv, wT2);
  qkv_kernel<<<dim3(NROW / 64), dim3(256), 0, stream>>>(x, wT2, q_ws, k_ws, vT);
  attn_kernel<<<dim3(512), dim3(256), 0, stream>>>(q_ws, k_ws, vT, out);
}

// Round 21
// 70.559 us; speedup vs baseline: 1.5268x; 1.3712x over previous
//
#include <hip/hip_runtime.h>
#include <hip/hip_bf16.h>

// Head: k/q/v projection + causal softmax attention, single head.
// B=8, T=4096, C=1024, H=64. All inputs fp32; output fp32.
//   k0: wT2 = [Wq|Wk|Wv]^T per-chunk staged layout (q cols pre-scaled).
//   k1: qkv v8 (measured ~21us = x HBM floor); epilogue now writes K and V in
//       MFMA-FRAGMENT-READY layouts (see below).
//   k2: flash attention. R20 diagnosis: 8 VMEM instrs/TILE32 each touched 32
//       discontiguous 32B segments (~256 txn/TILE32) -> address-pipe bound;
//       occupancy/pipelining levers were null (R16/R17/R19/R20). Now each
//       K/V fragment load is base + lane*16B = ONE contiguous 1KB wave-read.
//       kf[b][sb][j][hi][qi]: 16B = K[sb*32+qi][16j+8hi..+7]
//       vf[b][sb][o][j2][hi][qi]: 16B = V^T[o*32+qi][sb*32+16j2+8hi..+7]

#define HS 64
#define NE 1024
#define NB 8
#define TS 4096
#define NROW (NB * TS)  // 32768

#define QKV_BUF 20480   // per buffer: 12288 W + 8192 X
#define QKV_XB  12288

typedef __attribute__((ext_vector_type(4)))  float f32x4;
typedef __attribute__((ext_vector_type(16))) float f32x16;
typedef __attribute__((ext_vector_type(8)))  short s16x8;   // bf16x8 MFMA fragment
typedef __attribute__((ext_vector_type(4)))  float vfloat4;

__device__ __forceinline__ unsigned short f2bf(float x) {
  return __builtin_bit_cast(unsigned short, __float2bfloat16(x));
}
__device__ __forceinline__ unsigned pkbf(float lo, float hi) {
  return (unsigned)f2bf(lo) | ((unsigned)f2bf(hi) << 16);
}

union ABFrag { s16x8 v; unsigned d[4]; };

__device__ __forceinline__ void gl_lds16(const void* g, const unsigned char* l) {
  __builtin_amdgcn_global_load_lds(
      (const __attribute__((address_space(1))) unsigned int*)(g),
      (__attribute__((address_space(3))) unsigned int*)(l), 16, 0, 0);
}

// ---------------- kernel 0: weight transpose+cast, per-chunk layout ----
__global__ __launch_bounds__(256) void wt_kernel(const float* __restrict__ Wk,
                                                 const float* __restrict__ Wq,
                                                 const float* __restrict__ Wv,
                                                 unsigned short* __restrict__ wT2) {
  int gid = blockIdx.x * 256 + threadIdx.x;   // 0..196607
  int j = gid & 7;
  int t1 = gid >> 3;          // 0..24575
  int sk = t1 % 768;
  int c  = t1 / 768;          // 0..31
  int g = sk / 192, n = sk % 192;
  int k = c * 32 + g * 8 + j;
  const float* W = (n < 64) ? Wq : (n < 128) ? Wk : Wv;
  float s = (n < 64) ? 0.18033688011112042f : 1.0f;  // 0.125 * log2(e)
  wT2[gid] = f2bf(W[k * 64 + (n & 63)] * s);
}

// ---------------- kernel 1: fused QKV projection v8 ----------------
__global__ __launch_bounds__(256, 4) void qkv_kernel(const float* __restrict__ x,
                                                     const unsigned short* __restrict__ wT2,
                                                     unsigned short* __restrict__ q_ws,
                                                     unsigned short* __restrict__ kf,
                                                     unsigned short* __restrict__ vf) {
  __shared__ __align__(16) unsigned char smem[2 * QKV_BUF];  // 40960 B
  const int t = threadIdx.x;
  const int w = t >> 6, lane = t & 63;
  const int g = lane >> 4, nn = lane & 15;
  const int m0blk = blockIdx.x * 64;
  const int m0 = m0blk + w * 16;

  f32x4 acc[12];
#pragma unroll
  for (int i = 0; i < 12; ++i) acc[i] = f32x4{0.f, 0.f, 0.f, 0.f};

  const unsigned short* wsrcA = wT2 + (size_t)(w * 192 + lane) * 8;  // +c*6144
  const int wd0 = w * 3072;                                          // +p*1024
  const float* xs0 = x + (size_t)(m0blk + w * 16 + 0 + (lane >> 3)) * NE + (lane & 7) * 4;
  const float* xs1 = x + (size_t)(m0blk + w * 16 + 8 + (lane >> 3)) * NE + (lane & 7) * 4;
  const int xd0 = QKV_XB + w * 2048;
  const int xd1 = xd0 + 1024;

  const int abase = QKV_XB + (w * 16 + nn) * 128 + g * 32;
  const int wbase = (g * 192 + nn) * 16;

#define ISSUE(C)                                                               \
  {                                                                            \
    unsigned char* db_ = smem + ((C) & 1) * QKV_BUF;                           \
    gl_lds16(wsrcA + (size_t)(C) * 6144, db_ + wd0);                           \
    gl_lds16(wsrcA + (size_t)(C) * 6144 + 512, db_ + wd0 + 1024);              \
    gl_lds16(wsrcA + (size_t)(C) * 6144 + 1024, db_ + wd0 + 2048);             \
    gl_lds16(xs0 + (C) * 32, db_ + xd0);                                       \
    gl_lds16(xs1 + (C) * 32, db_ + xd1);                                       \
  }

  ISSUE(0)
  __builtin_amdgcn_sched_barrier(0);
  ISSUE(1)
  __builtin_amdgcn_sched_barrier(0);

#define PHASE(C, VM, DOISS)                                                    \
  {                                                                            \
    asm volatile("s_waitcnt vmcnt(" #VM ")" ::: "memory");                     \
    __builtin_amdgcn_s_barrier();                                              \
    __builtin_amdgcn_sched_barrier(0);                                         \
    const unsigned char* bb_ = smem + ((C) & 1) * QKV_BUF;                     \
    const vfloat4 a0_ = *(const vfloat4*)(bb_ + abase);                        \
    const vfloat4 a1_ = *(const vfloat4*)(bb_ + abase + 16);                   \
    ABFrag af;                                                                 \
    af.d[0] = pkbf(a0_.x, a0_.y); af.d[1] = pkbf(a0_.z, a0_.w);                \
    af.d[2] = pkbf(a1_.x, a1_.y); af.d[3] = pkbf(a1_.z, a1_.w);                \
    _Pragma("unroll")                                                          \
    for (int i = 0; i < 12; ++i) {                                             \
      const s16x8 bf = *(const s16x8*)(bb_ + wbase + i * 256);                 \
      acc[i] = __builtin_amdgcn_mfma_f32_16x16x32_bf16(af.v, bf, acc[i], 0, 0, 0); \
    }                                                                          \
    __builtin_amdgcn_sched_barrier(0);                                         \
    __builtin_amdgcn_s_barrier();                                              \
    __builtin_amdgcn_sched_barrier(0);                                         \
    if (DOISS) { ISSUE((C) + 2) }                                              \
    __builtin_amdgcn_sched_barrier(0);                                         \
  }

#pragma unroll
  for (int c = 0; c < 30; ++c) PHASE(c, 5, 1)
  PHASE(30, 5, 0)
  PHASE(31, 0, 0)
#undef PHASE
#undef ISSUE

  // ---- epilogue: D row = m0 + 4g + j, col = 16i + nn ----
  // q: row-major q_ws[rr][c].
  // K (c in [64,128)): h=c-64 -> kf idx = b*262144 + sb*2048 + (h>>4)*512
  //   + ((h>>3)&1)*256 + (t&31)*8 + (h&7)
  // V (c in [128,192)): h=c-128 -> vf idx = b*262144 + sb*2048 + (h>>5)*1024
  //   + ((t>>4)&1)*512 + ((t>>3)&1)*256 + (h&31)*8 + (t&7)
  const int rbase = m0 + 4 * g;
#pragma unroll
  for (int i = 0; i < 12; ++i) {
    const int c = 16 * i + nn;
#pragma unroll
    for (int j = 0; j < 4; ++j) {
      const int rr = rbase + j;
      const unsigned short hval = f2bf(acc[i][j]);
      const int b = rr >> 12, tt = rr & 4095;
      if (c < 64) {
        q_ws[(size_t)rr * HS + c] = hval;
      } else if (c < 128) {
        const int h = c - 64;
        const size_t idx = (size_t)b * 262144 + (size_t)(tt >> 5) * 2048 +
                           (h >> 4) * 512 + ((h >> 3) & 1) * 256 +
                           (tt & 31) * 8 + (h & 7);
        kf[idx] = hval;
      } else {
        const int h = c - 128;
        const size_t idx = (size_t)b * 262144 + (size_t)(tt >> 5) * 2048 +
                           (h >> 5) * 1024 + ((tt >> 4) & 1) * 512 +
                           ((tt >> 3) & 1) * 256 + (h & 31) * 8 + (tt & 7);
        vf[idx] = hval;
      }
    }
  }
}

// ---------------- kernel 2: causal flash attention, 32x32 lane-local -------
// S^T(32kv x 32q) = sum_kk mfma32x32x16(K-frag, Q^T-frag). Lane (qi,hi) holds
// st_[r] = S^T[kv=(r&3)+8*(r>>2)+4hi][q=qi]; the other 16 kv live in lane^32.
// K/V fragment loads: base + lane*16B, contiguous 1KB per instruction.
#define TILE32(S0, DIAG, QF, M_RUN, L_RUN, O)                                  \
  {                                                                            \
    const unsigned short* kb_ = kfb + (size_t)((S0) >> 5) * 2048 + lane * 8;   \
    const unsigned short* vb_ = vfb + (size_t)((S0) >> 5) * 2048 + lane * 8;   \
    const s16x8 ka0_ = *(const s16x8*)(kb_);                                   \
    const s16x8 ka1_ = *(const s16x8*)(kb_ + 512);                             \
    const s16x8 ka2_ = *(const s16x8*)(kb_ + 1024);                            \
    const s16x8 ka3_ = *(const s16x8*)(kb_ + 1536);                            \
    f32x16 st_;                                                                \
    _Pragma("unroll") for (int r = 0; r < 16; ++r) st_[r] = 0.f;               \
    __builtin_amdgcn_s_setprio(1);                                             \
    st_ = __builtin_amdgcn_mfma_f32_32x32x16_bf16(ka0_, QF[0], st_, 0, 0, 0);  \
    st_ = __builtin_amdgcn_mfma_f32_32x32x16_bf16(ka1_, QF[1], st_, 0, 0, 0);  \
    st_ = __builtin_amdgcn_mfma_f32_32x32x16_bf16(ka2_, QF[2], st_, 0, 0, 0);  \
    st_ = __builtin_amdgcn_mfma_f32_32x32x16_bf16(ka3_, QF[3], st_, 0, 0, 0);  \
    __builtin_amdgcn_s_setprio(0);                                             \
    if (DIAG) {                                                                \
      _Pragma("unroll") for (int r = 0; r < 16; ++r) {                         \
        const int kvl_ = (r & 3) + 8 * (r >> 2) + hi4;                         \
        if (kvl_ > qi) st_[r] = -1e30f;                                        \
      }                                                                        \
    }                                                                          \
    float mx_ =                                                                \
      fmaxf(fmaxf(fmaxf(fmaxf(st_[0], st_[1]), fmaxf(st_[2], st_[3])),         \
                  fmaxf(fmaxf(st_[4], st_[5]), fmaxf(st_[6], st_[7]))),        \
            fmaxf(fmaxf(fmaxf(st_[8], st_[9]), fmaxf(st_[10], st_[11])),       \
                  fmaxf(fmaxf(st_[12], st_[13]), fmaxf(st_[14], st_[15]))));   \
    mx_ = fmaxf(mx_, __shfl_xor(mx_, 32, 64));                                 \
    const float mn_ = fmaxf(M_RUN, mx_);                                       \
    if (__ballot(mn_ > M_RUN)) {                                               \
      const float fs_ = __builtin_amdgcn_exp2f(M_RUN - mn_);                   \
      _Pragma("unroll") for (int r = 0; r < 16; ++r) {                         \
        O[0][r] *= fs_; O[1][r] *= fs_;                                        \
      }                                                                        \
      L_RUN *= fs_;                                                            \
      M_RUN = mn_;                                                             \
    }                                                                          \
    float p_[16];                                                              \
    _Pragma("unroll") for (int r = 0; r < 16; ++r)                             \
      p_[r] = __builtin_amdgcn_exp2f(st_[r] - M_RUN);                          \
    float sm_ = ((p_[0] + p_[1]) + (p_[2] + p_[3])) +                          \
                ((p_[4] + p_[5]) + (p_[6] + p_[7]));                           \
    sm_ += ((p_[8] + p_[9]) + (p_[10] + p_[11])) +                             \
           ((p_[12] + p_[13]) + (p_[14] + p_[15]));                            \
    sm_ += __shfl_xor(sm_, 32, 64);                                            \
    L_RUN += sm_;                                                              \
    const unsigned q01_ = pkbf(p_[0], p_[1]),   q23_ = pkbf(p_[2], p_[3]);     \
    const unsigned q45_ = pkbf(p_[4], p_[5]),   q67_ = pkbf(p_[6], p_[7]);     \
    const unsigned q89_ = pkbf(p_[8], p_[9]),   qab_ = pkbf(p_[10], p_[11]);   \
    const unsigned qcd_ = pkbf(p_[12], p_[13]), qef_ = pkbf(p_[14], p_[15]);   \
    const unsigned t01_ = (unsigned)__shfl_xor((int)q01_, 32, 64);             \
    const unsigned t23_ = (unsigned)__shfl_xor((int)q23_, 32, 64);             \
    const unsigned t45_ = (unsigned)__shfl_xor((int)q45_, 32, 64);             \
    const unsigned t67_ = (unsigned)__shfl_xor((int)q67_, 32, 64);             \
    const unsigned t89_ = (unsigned)__shfl_xor((int)q89_, 32, 64);             \
    const unsigned tab_ = (unsigned)__shfl_xor((int)qab_, 32, 64);             \
    const unsigned tcd_ = (unsigned)__shfl_xor((int)qcd_, 32, 64);             \
    const unsigned tef_ = (unsigned)__shfl_xor((int)qef_, 32, 64);             \
    ABFrag pf0_, pf1_;                                                         \
    pf0_.d[0] = hi ? t45_ : q01_;                                              \
    pf0_.d[1] = hi ? t67_ : q23_;                                              \
    pf0_.d[2] = hi ? q45_ : t01_;                                              \
    pf0_.d[3] = hi ? q67_ : t23_;                                              \
    pf1_.d[0] = hi ? tcd_ : q89_;                                              \
    pf1_.d[1] = hi ? tef_ : qab_;                                              \
    pf1_.d[2] = hi ? qcd_ : t89_;                                              \
    pf1_.d[3] = hi ? qef_ : tab_;                                              \
    const s16x8 vf00_ = *(const s16x8*)(vb_);                                  \
    const s16x8 vf01_ = *(const s16x8*)(vb_ + 512);                            \
    const s16x8 vf10_ = *(const s16x8*)(vb_ + 1024);                           \
    const s16x8 vf11_ = *(const s16x8*)(vb_ + 1536);                           \
    __builtin_amdgcn_s_setprio(1);                                             \
    O[0] = __builtin_amdgcn_mfma_f32_32x32x16_bf16(vf00_, pf0_.v, O[0], 0,0,0);\
    O[0] = __builtin_amdgcn_mfma_f32_32x32x16_bf16(vf01_, pf1_.v, O[0], 0,0,0);\
    O[1] = __builtin_amdgcn_mfma_f32_32x32x16_bf16(vf10_, pf0_.v, O[1], 0,0,0);\
    O[1] = __builtin_amdgcn_mfma_f32_32x32x16_bf16(vf11_, pf1_.v, O[1], 0,0,0);\
    __builtin_amdgcn_s_setprio(0);                                             \
  }

__global__ __launch_bounds__(256, 2) void attn_kernel(const unsigned short* __restrict__ q_ws,
                                                      const unsigned short* __restrict__ kf,
                                                      const unsigned short* __restrict__ vf,
                                                      float* __restrict__ out) {
  __shared__ float o_sm[2][4][16][68];   // [tile][wave][row-half][h] 34.8KB
  __shared__ float lm_sm[2][4][32][2];   // 2KB

  const int wv = threadIdx.x >> 6, lane = threadIdx.x & 63;
  const int qi = lane & 31, hi = lane >> 5;
  const int hi8 = 8 * hi, hi4 = 4 * hi;

  const int bid = blockIdx.x;             // 0..511
  const int b = bid & 7;                  // batch <-> XCD alignment
  const int pr = bid >> 3;                // 0..63
  const int tiA = pr, tiB = 127 - pr;     // paired long/short 32-row tiles
  const int t0A = tiA * 32, t0B = tiB * 32;

  const unsigned short* kfb = kf + (size_t)b * 262144;
  const unsigned short* vfb = vf + (size_t)b * 262144;
  const unsigned short* qrA = q_ws + (size_t)(b * TS + t0A + qi) * HS + hi8;
  const unsigned short* qrB = q_ws + (size_t)(b * TS + t0B + qi) * HS + hi8;

  s16x8 qfA[4], qfB[4];
#pragma unroll
  for (int kk = 0; kk < 4; ++kk) {
    qfA[kk] = *(const s16x8*)(qrA + 16 * kk);
    qfB[kk] = *(const s16x8*)(qrB + 16 * kk);
  }

  f32x16 oA[2], oB[2];
#pragma unroll
  for (int r = 0; r < 16; ++r) { oA[0][r] = 0.f; oA[1][r] = 0.f; oB[0][r] = 0.f; oB[1][r] = 0.f; }
  float mA = -1e30f, lA = 0.f, mB = -1e30f, lB = 0.f;

  const int ntA = tiA + 1, ntB = tiB + 1;
  for (int it = wv; it < ntB; it += 4) {
    const int s0 = it * 32;
    if (it < ntA) TILE32(s0, it == tiA, qfA, mA, lA, oA)
    TILE32(s0, it == tiB, qfB, mB, lB, oB)
  }

  // ---- epilogue: two-row-half parallel A/B merge through 36KB scratch ----
  if (lane < 32) {
    lm_sm[0][wv][lane][0] = mA; lm_sm[0][wv][lane][1] = lA;
    lm_sm[1][wv][lane][0] = mB; lm_sm[1][wv][lane][1] = lB;
  }
  const int q8 = (threadIdx.x >> 3) & 15;   // merge row within half
  const int h0 = (threadIdx.x & 7) * 8;     // merge h-group
  const int X  = threadIdx.x >> 7;          // merge tile (0=A, 1=B)
  const int t0X = X ? t0B : t0A;

#pragma unroll
  for (int P = 0; P < 2; ++P) {
    if ((qi >> 4) == P) {
      const int qr = qi & 15;
#pragma unroll
      for (int ht = 0; ht < 2; ++ht)
#pragma unroll
        for (int r = 0; r < 16; ++r) {
          const int h = ht * 32 + (r & 3) + 8 * (r >> 2) + hi4;
          o_sm[0][wv][qr][h] = oA[ht][r];
          o_sm[1][wv][qr][h] = oB[ht][r];
        }
    }
    __syncthreads();
    {
      const int q = 16 * P + q8;
      const float m0v = lm_sm[X][0][q][0], m1v = lm_sm[X][1][q][0];
      const float m2v = lm_sm[X][2][q][0], m3v = lm_sm[X][3][q][0];
      const float M = fmaxf(fmaxf(m0v, m1v), fmaxf(m2v, m3v));
      const float w0 = __builtin_amdgcn_exp2f(m0v - M);
      const float w1 = __builtin_amdgcn_exp2f(m1v - M);
      const float w2 = __builtin_amdgcn_exp2f(m2v - M);
      const float w3 = __builtin_amdgcn_exp2f(m3v - M);
      const float L = w0 * lm_sm[X][0][q][1] + w1 * lm_sm[X][1][q][1] +
                      w2 * lm_sm[X][2][q][1] + w3 * lm_sm[X][3][q][1];
      const float inv = 1.0f / L;
      float rv[8];
#pragma unroll
      for (int j = 0; j < 8; ++j)
        rv[j] = (w0 * o_sm[X][0][q8][h0 + j] + w1 * o_sm[X][1][q8][h0 + j] +
                 w2 * o_sm[X][2][q8][h0 + j] + w3 * o_sm[X][3][q8][h0 + j]) * inv;
      float* ob = out + ((size_t)(b * TS + t0X + q)) * HS + h0;
      *(float4*)(ob)     = float4{rv[0], rv[1], rv[2], rv[3]};
      *(float4*)(ob + 4) = float4{rv[4], rv[5], rv[6], rv[7]};
    }
    if (P == 0) __syncthreads();
  }
}

extern "C" void kernel_launch(void* const* d_in, const int* in_sizes, int n_in,
                              void* d_out, int out_size, void* d_ws, size_t ws_size,
                              hipStream_t stream) {
  const float* x  = (const float*)d_in[0];
  const float* Wk = (const float*)d_in[1];
  const float* Wq = (const float*)d_in[2];
  const float* Wv = (const float*)d_in[3];
  float* out = (float*)d_out;

  unsigned short* wT2  = (unsigned short*)d_ws;
  unsigned short* q_ws = wT2 + 192 * 1024;
  unsigned short* kf   = q_ws + (size_t)NROW * HS;
  unsigned short* vf   = kf + (size_t)NROW * HS;

  wt_kernel<<<dim3(768), dim3(256), 0, stream>>>(Wk, Wq, Wv, wT2);
  qkv_kernel<<<dim3(NROW / 64), dim3(256), 0, stream>>>(x, wT2, q_ws, kf, vf);
  attn_kernel<<<dim3(512), dim3(256), 0, stream>>>(q_ws, kf, vf, out);
}